// Round 1
// baseline (1244.506 us; speedup 1.0000x reference)
//
#include <hip/hip_runtime.h>
#include <hip/hip_bf16.h>
#include <math.h>

#define NUM_EMB 8192
#define EMB_DIM 256
#define NTOK    16384      // 16 * 32 * 32
#define HW      1024       // 32*32
#define QELEMS  4194304    // 16 * 256 * 1024
#define DECAY   0.99f
#define COMMIT  0.25f
#define EPS_    1e-5f

#define BM 128
#define BK 128
#define BD 32
#define SPLITK 8
#define KSLICE (NUM_EMB / SPLITK)   // 1024

// ---------------- k_esq: per-code squared norm ----------------
__global__ __launch_bounds__(256)
void k_esq(const float* __restrict__ emb, float* __restrict__ esq) {
    int k = blockIdx.x * 4 + (threadIdx.x >> 6);
    int lane = threadIdx.x & 63;
    const float* row = emb + (size_t)k * EMB_DIM;
    float4 v = *(const float4*)(row + lane * 4);
    float s = v.x * v.x + v.y * v.y + v.z * v.z + v.w * v.w;
    #pragma unroll
    for (int m = 32; m >= 1; m >>= 1) s += __shfl_xor(s, m);
    if (lane == 0) esq[k] = s;
}

// ---------------- k_dist: fp32 tiled GEMM + per-token argmin ----------------
__global__ __launch_bounds__(256, 2)
void k_dist(const float* __restrict__ x, const float* __restrict__ emb,
            const float* __restrict__ esq,
            float* __restrict__ minval, int* __restrict__ minidx) {
    __shared__ float As[BD][BM + 4];
    __shared__ float Bs[BD][BK + 4];

    const int tid   = threadIdx.x;
    const int bid   = blockIdx.x;
    const int mtile = bid & 127;
    const int slice = bid >> 7;
    const int m0    = mtile * BM;
    const int b     = m0 >> 10;          // batch
    const int hw0   = m0 & 1023;
    const float* xbase = x + (size_t)b * EMB_DIM * HW + hw0;  // x[b, d, hw0+m]
    const int k0base = slice * KSLICE;

    const int tm = tid >> 4;   // 0..15 : row group (8 rows each)
    const int tk = tid & 15;   // 0..15 : col group (8 cols each)

    float bestv[8];
    int   besti[8];
    #pragma unroll
    for (int i = 0; i < 8; i++) { bestv[i] = 3.4e38f; besti[i] = 0x7fffffff; }

    for (int kt = 0; kt < KSLICE; kt += BK) {
        const int k0 = k0base + kt;
        float acc[8][8];
        #pragma unroll
        for (int i = 0; i < 8; i++)
            #pragma unroll
            for (int j = 0; j < 8; j++) acc[i][j] = 0.0f;

        for (int d0 = 0; d0 < EMB_DIM; d0 += BD) {
            __syncthreads();
            // Stage A-tile: As[dd][m] <- x[b, d0+dd, hw0+m]  (contiguous along m)
            {
                const int dd = tid >> 3;      // 0..31
                const int u  = tid & 7;       // 0..7
                const float* src = xbase + (size_t)(d0 + dd) * HW;
                #pragma unroll
                for (int r = 0; r < 4; r++) {
                    int m = (u + 8 * r) * 4;
                    float4 v = *(const float4*)(src + m);
                    *(float4*)(&As[dd][m]) = v;
                }
            }
            // Stage B-tile (transpose): Bs[dd][kk] <- emb[k0+kk, d0+dd]
            {
                const int c    = tid & 7;     // d-chunk of 4
                const int krow = tid >> 3;    // 0..31
                #pragma unroll
                for (int p = 0; p < 4; p++) {
                    int kk = krow + 32 * p;
                    const float* src = emb + (size_t)(k0 + kk) * EMB_DIM + d0 + c * 4;
                    float4 v = *(const float4*)src;
                    Bs[c * 4 + 0][kk] = v.x;
                    Bs[c * 4 + 1][kk] = v.y;
                    Bs[c * 4 + 2][kk] = v.z;
                    Bs[c * 4 + 3][kk] = v.w;
                }
            }
            __syncthreads();

            #pragma unroll
            for (int dd = 0; dd < BD; dd++) {
                float a[8], bq[8];
                *(float4*)(&a[0])  = *(const float4*)(&As[dd][tm * 8]);
                *(float4*)(&a[4])  = *(const float4*)(&As[dd][tm * 8 + 4]);
                *(float4*)(&bq[0]) = *(const float4*)(&Bs[dd][tk * 8]);
                *(float4*)(&bq[4]) = *(const float4*)(&Bs[dd][tk * 8 + 4]);
                #pragma unroll
                for (int i = 0; i < 8; i++)
                    #pragma unroll
                    for (int j = 0; j < 8; j++)
                        acc[i][j] = fmaf(a[i], bq[j], acc[i][j]);
            }
        }

        // Epilogue: distances + argmin for this k-tile
        float ev[8];
        #pragma unroll
        for (int j = 0; j < 8; j++) ev[j] = esq[k0 + tk * 8 + j];

        #pragma unroll
        for (int i = 0; i < 8; i++) {
            float bv = 3.4e38f; int bi = 0x7fffffff;
            #pragma unroll
            for (int j = 0; j < 8; j++) {
                float dv = fmaf(-2.0f, acc[i][j], ev[j]);
                int   ki = k0 + tk * 8 + j;
                if (dv < bv || (dv == bv && ki < bi)) { bv = dv; bi = ki; }
            }
            // butterfly across the 16 tk lanes (tie -> lower index)
            #pragma unroll
            for (int mask = 1; mask <= 8; mask <<= 1) {
                float ov = __shfl_xor(bv, mask);
                int   oi = __shfl_xor(bi, mask);
                if (ov < bv || (ov == bv && oi < bi)) { bv = ov; bi = oi; }
            }
            if (bv < bestv[i] || (bv == bestv[i] && bi < besti[i])) {
                bestv[i] = bv; besti[i] = bi;
            }
        }
    }

    if (tk == 0) {
        #pragma unroll
        for (int i = 0; i < 8; i++) {
            int m = m0 + tm * 8 + i;
            minval[(size_t)slice * NTOK + m] = bestv[i];
            minidx[(size_t)slice * NTOK + m] = besti[i];
        }
    }
}

// ---------------- k_merge: reduce split-K slices ----------------
__global__ __launch_bounds__(256)
void k_merge(const float* __restrict__ minval, const int* __restrict__ minidx,
             int* __restrict__ idx_i32, float* __restrict__ counts,
             float* __restrict__ out_idxf) {
    int n = blockIdx.x * 256 + threadIdx.x;
    float bv = 3.4e38f; int bi = 0x7fffffff;
    #pragma unroll
    for (int s = 0; s < SPLITK; s++) {
        float v = minval[(size_t)s * NTOK + n];
        int  ii = minidx[(size_t)s * NTOK + n];
        if (v < bv || (v == bv && ii < bi)) { bv = v; bi = ii; }
    }
    idx_i32[n] = bi;
    out_idxf[n] = (float)bi;
    atomicAdd(&counts[bi], 1.0f);
}

// ---------------- k_fused: q_st + dw scatter + loss ----------------
__global__ __launch_bounds__(256)
void k_fused(const float* __restrict__ x, const float* __restrict__ emb,
             const int* __restrict__ idx_i32,
             float* __restrict__ out_qst, float* __restrict__ dw,
             float* __restrict__ loss_acc) {
    int e  = blockIdx.x * 256 + threadIdx.x;    // NCHW linear
    int b  = e >> 18;            // / (256*1024)
    int r  = e & 262143;
    int d  = r >> 10;
    int hw = r & 1023;
    int n  = (b << 10) | hw;
    int k  = idx_i32[n];
    float xv = x[e];
    float q  = emb[(size_t)k * EMB_DIM + d];
    float diff = q - xv;
    out_qst[e] = xv + diff;      // straight-through, same fp ops as reference
    atomicAdd(&dw[(size_t)k * EMB_DIM + d], xv);

    float sq = diff * diff;
    #pragma unroll
    for (int m = 32; m >= 1; m >>= 1) sq += __shfl_xor(sq, m);
    __shared__ float wsum[4];
    int lane = threadIdx.x & 63, wid = threadIdx.x >> 6;
    if (lane == 0) wsum[wid] = sq;
    __syncthreads();
    if (threadIdx.x == 0)
        atomicAdd(loss_acc, wsum[0] + wsum[1] + wsum[2] + wsum[3]);
}

// ---------------- k_stats: n, perplexity, loss (single block) ----------------
__global__ __launch_bounds__(256)
void k_stats(const float* __restrict__ counts, const float* __restrict__ cs,
             const float* __restrict__ loss_acc,
             float* __restrict__ n_out, float* __restrict__ out) {
    int tid = threadIdx.x;
    float s1 = 0.0f, s2 = 0.0f;
    for (int k = tid; k < NUM_EMB; k += 256) {
        float c = counts[k];
        s1 += cs[k] * DECAY + (1.0f - DECAY) * c;
        float p = c / (float)NTOK;
        s2 += p * logf(p + 1e-10f);
    }
    #pragma unroll
    for (int m = 32; m >= 1; m >>= 1) {
        s1 += __shfl_xor(s1, m);
        s2 += __shfl_xor(s2, m);
    }
    __shared__ float w1[4], w2[4];
    int lane = tid & 63, wid = tid >> 6;
    if (lane == 0) { w1[wid] = s1; w2[wid] = s2; }
    __syncthreads();
    if (tid == 0) {
        float n  = w1[0] + w1[1] + w1[2] + w1[3];
        float e2 = w2[0] + w2[1] + w2[2] + w2[3];
        n_out[0] = n;
        out[4194305] = expf(-e2);                           // perplexity
        out[0] = COMMIT * loss_acc[0] / (float)QELEMS;      // loss
    }
}

// ---------------- k_final: smoothing + EMA outputs ----------------
__global__ __launch_bounds__(256)
void k_final(const float* __restrict__ cs, const float* __restrict__ emaw,
             const float* __restrict__ counts, const float* __restrict__ dw,
             const float* __restrict__ n_in,
             float* __restrict__ out_emb, float* __restrict__ out_cs,
             float* __restrict__ out_emaw) {
    int k = blockIdx.x;
    int d = threadIdx.x;
    float n = n_in[0];
    float pre  = cs[k] * DECAY + (1.0f - DECAY) * counts[k];
    float cssm = (pre + EPS_) / (n + (float)NUM_EMB * EPS_) * n;
    size_t o = (size_t)k * EMB_DIM + d;
    float w = emaw[o] * DECAY + (1.0f - DECAY) * dw[o];
    out_emaw[o] = w;
    out_emb[o]  = w / cssm;
    if (d == 0) out_cs[k] = cssm;
}

extern "C" void kernel_launch(void* const* d_in, const int* in_sizes, int n_in,
                              void* d_out, int out_size, void* d_ws, size_t ws_size,
                              hipStream_t stream) {
    const float* x    = (const float*)d_in[0];   // [16,256,32,32]
    const float* emb  = (const float*)d_in[1];   // [8192,256]
    const float* cs   = (const float*)d_in[2];   // [8192]
    const float* emaw = (const float*)d_in[3];   // [8192,256]
    float* out = (float*)d_out;

    // workspace layout (floats)
    float* ws      = (float*)d_ws;
    float* esq     = ws;                         // 8192
    float* minval  = esq + NUM_EMB;              // SPLITK*NTOK = 131072
    int*   minidx  = (int*)(minval + (size_t)SPLITK * NTOK);  // 131072
    float* counts  = (float*)(minidx + (size_t)SPLITK * NTOK); // 8192
    float* dw      = counts + NUM_EMB;           // 2097152
    float* loss_acc= dw + (size_t)NUM_EMB * EMB_DIM; // 1
    float* n_scal  = loss_acc + 1;               // 1
    int*   idx_i32 = (int*)(n_scal + 1);         // 16384

    // zero counts + dw + loss_acc (contiguous)
    hipMemsetAsync(counts, 0, ((size_t)NUM_EMB + (size_t)NUM_EMB * EMB_DIM + 1) * sizeof(float), stream);

    k_esq  <<<NUM_EMB / 4, 256, 0, stream>>>(emb, esq);
    k_dist <<<128 * SPLITK, 256, 0, stream>>>(x, emb, esq, minval, minidx);
    k_merge<<<NTOK / 256, 256, 0, stream>>>(minval, minidx, idx_i32, counts,
                                            out + 8396802);
    k_fused<<<QELEMS / 256, 256, 0, stream>>>(x, emb, idx_i32, out + 1, dw, loss_acc);
    k_stats<<<1, 256, 0, stream>>>(counts, cs, loss_acc, n_scal, out);
    k_final<<<NUM_EMB, 256, 0, stream>>>(cs, emaw, counts, dw, n_scal,
                                         out + 4194306, out + 6291458, out + 6299650);
}

// Round 2
// 544.109 us; speedup vs baseline: 2.2872x; 2.2872x over previous
//
#include <hip/hip_runtime.h>
#include <hip/hip_bf16.h>
#include <math.h>

#define NUM_EMB 8192
#define EMB_DIM 256
#define NTOK    16384      // 16 * 32 * 32
#define HW      1024
#define QELEMS  4194304    // 16 * 256 * 1024
#define DECAY   0.99f
#define OMD     0.01f      // float32(1.0 - 0.99) == float32(0.01)
#define COMMIT  0.25f
#define EPS_    1e-5f

typedef _Float16 h8 __attribute__((ext_vector_type(8)));
typedef _Float16 h4 __attribute__((ext_vector_type(4)));
typedef float    f4 __attribute__((ext_vector_type(4)));

#define GLD16(gptr, lptr) \
  __builtin_amdgcn_global_load_lds((const __attribute__((address_space(1))) void*)(gptr), \
                                   (__attribute__((address_space(3))) void*)(lptr), 16, 0, 0)

// ---------------- k_prep_x: x (NCHW fp32) -> A' fp16 hi/lo in MFMA fragment order ----
// A' layout: [mt 0..1023][chunk 0..15][lane 0..63][8 halves]; chunks 0..7 = hi (d = c*32
// + (lane>>4)*8 + j), chunks 8..15 = lo. token = mt*16 + (lane&15).
__global__ __launch_bounds__(256)
void k_prep_x(const float* __restrict__ x, _Float16* __restrict__ Ap) {
    int g = blockIdx.x * 256 + threadIdx.x;   // 0..524287
    int lane = g & 63;
    int kc = (g >> 6) & 7;
    int mt = g >> 9;
    int tok = mt * 16 + (lane & 15);
    int b = tok >> 10, hw = tok & 1023;
    int d0 = kc * 32 + (lane >> 4) * 8;
    const float* src = x + (size_t)b * 262144 + (size_t)d0 * 1024 + hw;
    h8 hi, lo;
    #pragma unroll
    for (int u = 0; u < 8; u++) {
        float v = src[(size_t)u * 1024];
        _Float16 h = (_Float16)v;
        hi[u] = h;
        lo[u] = (_Float16)(v - (float)h);
    }
    *(h8*)(Ap + ((size_t)(mt * 16 + kc) * 64 + lane) * 8) = hi;
    *(h8*)(Ap + ((size_t)(mt * 16 + kc + 8) * 64 + lane) * 8) = lo;
}

// ---------------- k_prep_e: embedding -> B' fp16 hi/lo, same fragment order ----------
__global__ __launch_bounds__(256)
void k_prep_e(const float* __restrict__ emb, _Float16* __restrict__ Bp) {
    int g = blockIdx.x * 256 + threadIdx.x;   // 0..262143
    int lane = g & 63;
    int kc = (g >> 6) & 7;
    int nt = g >> 9;
    int n = nt * 16 + (lane & 15);
    int d0 = kc * 32 + (lane >> 4) * 8;
    const float* src = emb + (size_t)n * EMB_DIM + d0;
    h8 hi, lo;
    #pragma unroll
    for (int u = 0; u < 8; u++) {
        float v = src[u];
        _Float16 h = (_Float16)v;
        hi[u] = h;
        lo[u] = (_Float16)(v - (float)h);
    }
    *(h8*)(Bp + ((size_t)(nt * 16 + kc) * 64 + lane) * 8) = hi;
    *(h8*)(Bp + ((size_t)(nt * 16 + kc + 8) * 64 + lane) * 8) = lo;
}

// ---------------- k_esq: per-code squared norm (fp32 exact) ----------------
__global__ __launch_bounds__(256)
void k_esq(const float* __restrict__ emb, float* __restrict__ esq) {
    int k = blockIdx.x * 4 + (threadIdx.x >> 6);
    int lane = threadIdx.x & 63;
    const float* row = emb + (size_t)k * EMB_DIM;
    float4 v = *(const float4*)(row + lane * 4);
    float s = v.x * v.x + v.y * v.y + v.z * v.z + v.w * v.w;
    #pragma unroll
    for (int m = 32; m >= 1; m >>= 1) s += __shfl_xor(s, m);
    if (lane == 0) esq[k] = s;
}

// ---------------- k_dist: f16 hi/lo MFMA GEMM (K'=768) + fused argmin ----------------
// Tile 128x128, 4 waves (2x2 of 64x64), mfma_f32_16x16x32_f16, m97-style staging.
__global__ __launch_bounds__(256, 2)
void k_dist(const _Float16* __restrict__ Ap, const _Float16* __restrict__ Bp,
            const float* __restrict__ esq,
            float* __restrict__ minval, int* __restrict__ minidx) {
    __shared__ _Float16 Abuf[8 * 64 * 8];   // 8 KB: 8 m-tiles x 64 lanes x 16B
    __shared__ _Float16 Bbuf[8 * 64 * 8];   // 8 KB
    __shared__ float sv[2][128];
    __shared__ int   si[2][128];

    const int tid  = threadIdx.x;
    const int lane = tid & 63;
    const int w    = tid >> 6;
    const int wm   = w >> 1, wn = w & 1;
    const int bN   = blockIdx.x & 63;
    const int bM   = blockIdx.x >> 6;
    const int m0   = bM * 128, n0 = bN * 128;

    f4 acc[4][4] = {};

    #pragma unroll 1
    for (int kc = 0; kc < 24; ++kc) {
        // segment map: kc 0..7 -> xh*eh, 8..15 -> xh*el, 16..23 -> xl*eh
        const int ac = (kc >= 8) ? kc - 8 : kc;   // A' chunk (0..7 hi, 8..15 lo)
        const int bc = kc & 15;                    // B' chunk (0..7 hi, 8..15 lo)
        __syncthreads();
        {
            const int t0 = w * 2;
            const _Float16* gA0 = Ap + ((size_t)((bM * 8 + t0)     * 16 + ac) * 64 + lane) * 8;
            const _Float16* gA1 = Ap + ((size_t)((bM * 8 + t0 + 1) * 16 + ac) * 64 + lane) * 8;
            const _Float16* gB0 = Bp + ((size_t)((bN * 8 + t0)     * 16 + bc) * 64 + lane) * 8;
            const _Float16* gB1 = Bp + ((size_t)((bN * 8 + t0 + 1) * 16 + bc) * 64 + lane) * 8;
            GLD16(gA0, Abuf + t0 * 512);
            GLD16(gA1, Abuf + (t0 + 1) * 512);
            GLD16(gB0, Bbuf + t0 * 512);
            GLD16(gB1, Bbuf + (t0 + 1) * 512);
        }
        __syncthreads();

        h8 aF[4], bF[4];
        #pragma unroll
        for (int i = 0; i < 4; i++)
            aF[i] = *(const h8*)(Abuf + ((wm * 4 + i) * 64 + lane) * 8);
        #pragma unroll
        for (int j = 0; j < 4; j++)
            bF[j] = *(const h8*)(Bbuf + ((wn * 4 + j) * 64 + lane) * 8);
        #pragma unroll
        for (int i = 0; i < 4; i++)
            #pragma unroll
            for (int j = 0; j < 4; j++)
                acc[i][j] = __builtin_amdgcn_mfma_f32_16x16x32_f16(aF[i], bF[j], acc[i][j], 0, 0, 0);
    }

    // epilogue: dist = esq[n] - 2*dot; argmin over the block's 128 codes
    float ev[4];
    #pragma unroll
    for (int j = 0; j < 4; j++) ev[j] = esq[n0 + wn * 64 + j * 16 + (lane & 15)];

    #pragma unroll
    for (int i = 0; i < 4; i++) {
        #pragma unroll
        for (int reg = 0; reg < 4; reg++) {
            float bv = 3.4e38f; int bi = 0x7fffffff;
            #pragma unroll
            for (int j = 0; j < 4; j++) {
                float dv = fmaf(-2.0f, acc[i][j][reg], ev[j]);
                int ki = n0 + wn * 64 + j * 16 + (lane & 15);
                if (dv < bv || (dv == bv && ki < bi)) { bv = dv; bi = ki; }
            }
            #pragma unroll
            for (int mask = 1; mask <= 8; mask <<= 1) {
                float ov = __shfl_xor(bv, mask);
                int   oi = __shfl_xor(bi, mask);
                if (ov < bv || (ov == bv && oi < bi)) { bv = ov; bi = oi; }
            }
            if ((lane & 15) == 0) {
                int r = wm * 64 + i * 16 + ((lane >> 4) << 2) + reg;
                sv[wn][r] = bv; si[wn][r] = bi;
            }
        }
    }
    __syncthreads();
    if (tid < 128) {
        float v0 = sv[0][tid]; int i0 = si[0][tid];
        float v1 = sv[1][tid]; int i1 = si[1][tid];
        if (v1 < v0 || (v1 == v0 && i1 < i0)) { v0 = v1; i0 = i1; }
        minval[(size_t)bN * NTOK + m0 + tid] = v0;
        minidx[(size_t)bN * NTOK + m0 + tid] = i0;
    }
}

// ---------------- k_merge: reduce 64 N-slices ----------------
__global__ __launch_bounds__(256)
void k_merge(const float* __restrict__ minval, const int* __restrict__ minidx,
             int* __restrict__ idx_i32, float* __restrict__ counts,
             float* __restrict__ out_idxf) {
    int n = blockIdx.x * 256 + threadIdx.x;
    float bv = 3.4e38f; int bi = 0x7fffffff;
    for (int s = 0; s < 64; s++) {
        float v = minval[(size_t)s * NTOK + n];
        int  ii = minidx[(size_t)s * NTOK + n];
        if (v < bv || (v == bv && ii < bi)) { bv = v; bi = ii; }
    }
    idx_i32[n] = bi;
    out_idxf[n] = (float)bi;
    atomicAdd(&counts[bi], 1.0f);
}

// ---------------- k_offsets: exclusive prefix sum of counts; init cursor ------------
__global__ __launch_bounds__(256)
void k_offsets(const float* __restrict__ counts, int* __restrict__ offsets,
               int* __restrict__ cursor) {
    __shared__ int part[256];
    int t = threadIdx.x;
    int base = t * 32;
    int loc[32]; int s = 0;
    #pragma unroll
    for (int u = 0; u < 32; u++) { loc[u] = s; s += (int)counts[base + u]; }
    part[t] = s;
    __syncthreads();
    for (int off = 1; off < 256; off <<= 1) {
        int add = (t >= off) ? part[t - off] : 0;
        __syncthreads();
        part[t] += add;
        __syncthreads();
    }
    int excl = part[t] - s;
    #pragma unroll
    for (int u = 0; u < 32; u++) {
        int o = excl + loc[u];
        offsets[base + u] = o;
        cursor[base + u] = o;
    }
}

// ---------------- k_scatter: build inverted token lists ----------------
__global__ __launch_bounds__(256)
void k_scatter(const int* __restrict__ idx_i32, int* __restrict__ cursor,
               int* __restrict__ toklist) {
    int n = blockIdx.x * 256 + threadIdx.x;
    int k = idx_i32[n];
    int p = atomicAdd(&cursor[k], 1);
    toklist[p] = n;
}

// ---------------- k_dw: per-code row sums (x reconstructed from A' hi+lo) -----------
__global__ __launch_bounds__(64)
void k_dw(const _Float16* __restrict__ Ap, const float* __restrict__ counts,
          const int* __restrict__ offsets, const int* __restrict__ toklist,
          float* __restrict__ dw) {
    int k = blockIdx.x;
    int lane = threadIdx.x;
    int c = (int)counts[k];
    int off = offsets[k];
    int kc = lane >> 3, q = (lane >> 1) & 3, jst = (lane & 1) * 4;
    float a0 = 0, a1 = 0, a2 = 0, a3 = 0;
    for (int t = 0; t < c; t++) {
        int tok = toklist[off + t];
        int mt = tok >> 4, li = tok & 15;
        h4 hi = *(const h4*)(Ap + ((size_t)(mt * 16 + kc)     * 64 + q * 16 + li) * 8 + jst);
        h4 lo = *(const h4*)(Ap + ((size_t)(mt * 16 + kc + 8) * 64 + q * 16 + li) * 8 + jst);
        a0 += (float)hi[0] + (float)lo[0];
        a1 += (float)hi[1] + (float)lo[1];
        a2 += (float)hi[2] + (float)lo[2];
        a3 += (float)hi[3] + (float)lo[3];
    }
    float4 o; o.x = a0; o.y = a1; o.z = a2; o.w = a3;
    *(float4*)(dw + (size_t)k * EMB_DIM + lane * 4) = o;
}

// ---------------- k_qst: straight-through output + commitment loss ----------------
__global__ __launch_bounds__(256)
void k_qst(const float* __restrict__ x, const float* __restrict__ emb,
           const int* __restrict__ idx_i32, float* __restrict__ out_qst,
           float* __restrict__ loss_acc) {
    int t = blockIdx.x * 256 + threadIdx.x;   // 1M threads, 4 elems each
    int e = t * 4;
    int b = e >> 18;
    int r = e & 262143;
    int d = r >> 10;
    int hw = r & 1023;
    int nb = (b << 10) | hw;
    float4 xv = *(const float4*)(x + e);
    float q0 = emb[(size_t)idx_i32[nb + 0] * EMB_DIM + d];
    float q1 = emb[(size_t)idx_i32[nb + 1] * EMB_DIM + d];
    float q2 = emb[(size_t)idx_i32[nb + 2] * EMB_DIM + d];
    float q3 = emb[(size_t)idx_i32[nb + 3] * EMB_DIM + d];
    float d0 = q0 - xv.x, d1 = q1 - xv.y, d2 = q2 - xv.z, d3 = q3 - xv.w;
    float4 o; o.x = xv.x + d0; o.y = xv.y + d1; o.z = xv.z + d2; o.w = xv.w + d3;
    *(float4*)(out_qst + e) = o;

    float sq = d0 * d0 + d1 * d1 + d2 * d2 + d3 * d3;
    #pragma unroll
    for (int m = 32; m >= 1; m >>= 1) sq += __shfl_xor(sq, m);
    __shared__ float wsum[4];
    int lane = threadIdx.x & 63, wid = threadIdx.x >> 6;
    if (lane == 0) wsum[wid] = sq;
    __syncthreads();
    if (threadIdx.x == 0)
        atomicAdd(loss_acc, wsum[0] + wsum[1] + wsum[2] + wsum[3]);
}

// ---------------- k_stats: n, perplexity, loss (single block) ----------------
__global__ __launch_bounds__(256)
void k_stats(const float* __restrict__ counts, const float* __restrict__ cs,
             const float* __restrict__ loss_acc,
             float* __restrict__ n_out, float* __restrict__ out) {
    int tid = threadIdx.x;
    float s1 = 0.0f, s2 = 0.0f;
    for (int k = tid; k < NUM_EMB; k += 256) {
        float c = counts[k];
        s1 += cs[k] * DECAY + OMD * c;
        float p = c / (float)NTOK;
        s2 += p * logf(p + 1e-10f);
    }
    #pragma unroll
    for (int m = 32; m >= 1; m >>= 1) {
        s1 += __shfl_xor(s1, m);
        s2 += __shfl_xor(s2, m);
    }
    __shared__ float w1[4], w2[4];
    int lane = tid & 63, wid = tid >> 6;
    if (lane == 0) { w1[wid] = s1; w2[wid] = s2; }
    __syncthreads();
    if (tid == 0) {
        float n  = w1[0] + w1[1] + w1[2] + w1[3];
        float e2 = w2[0] + w2[1] + w2[2] + w2[3];
        n_out[0] = n;
        out[4194305] = expf(-e2);                        // perplexity
        out[0] = COMMIT * loss_acc[0] / (float)QELEMS;   // loss
    }
}

// ---------------- k_final: Laplace smoothing + EMA outputs ----------------
__global__ __launch_bounds__(256)
void k_final(const float* __restrict__ cs, const float* __restrict__ emaw,
             const float* __restrict__ counts, const float* __restrict__ dw,
             const float* __restrict__ n_in,
             float* __restrict__ out_emb, float* __restrict__ out_cs,
             float* __restrict__ out_emaw) {
    int k = blockIdx.x;
    int d = threadIdx.x;
    float n = n_in[0];
    float pre  = cs[k] * DECAY + OMD * counts[k];
    float cssm = (pre + EPS_) / (n + (float)NUM_EMB * EPS_) * n;
    size_t o = (size_t)k * EMB_DIM + d;
    float w = emaw[o] * DECAY + OMD * dw[o];
    out_emaw[o] = w;
    out_emb[o]  = w / cssm;
    if (d == 0) out_cs[k] = cssm;
}

extern "C" void kernel_launch(void* const* d_in, const int* in_sizes, int n_in,
                              void* d_out, int out_size, void* d_ws, size_t ws_size,
                              hipStream_t stream) {
    const float* x    = (const float*)d_in[0];   // [16,256,32,32]
    const float* emb  = (const float*)d_in[1];   // [8192,256]
    const float* cs   = (const float*)d_in[2];   // [8192]
    const float* emaw = (const float*)d_in[3];   // [8192,256]
    float* out = (float*)d_out;

    // workspace layout (bytes)
    char* W = (char*)d_ws;
    _Float16* Ap    = (_Float16*)(W);             // 16,777,216
    _Float16* Bp    = (_Float16*)(W + 16777216);  //  8,388,608
    float* minval   = (float*)(W + 25165824);     //  4,194,304
    int*   minidx   = (int*)  (W + 29360128);     //  4,194,304
    float* dw       = (float*)(W + 33554432);     //  8,388,608
    float* esq      = (float*)(W + 41943040);     //     32,768
    float* counts   = (float*)(W + 41975808);     //     32,768
    float* loss_acc = (float*)(W + 42008576);     //          4
    float* n_scal   = (float*)(W + 42008580);     //          4
    int*   offsets  = (int*)  (W + 42008584);     //     32,768
    int*   cursor   = (int*)  (W + 42041352);     //     32,768
    int*   toklist  = (int*)  (W + 42074120);     //     65,536
    int*   idx_i32  = (int*)  (W + 42139656);     //     65,536  (end ~42.2 MB)

    hipMemsetAsync(counts, 0, 32768 + 8, stream);   // counts + loss_acc + n_scal

    k_prep_x <<<2048, 256, 0, stream>>>(x, Ap);
    k_prep_e <<<1024, 256, 0, stream>>>(emb, Bp);
    k_esq    <<<NUM_EMB / 4, 256, 0, stream>>>(emb, esq);
    k_dist   <<<8192, 256, 0, stream>>>(Ap, Bp, esq, minval, minidx);
    k_merge  <<<NTOK / 256, 256, 0, stream>>>(minval, minidx, idx_i32, counts,
                                              out + 8396802);
    k_offsets<<<1, 256, 0, stream>>>(counts, offsets, cursor);
    k_scatter<<<NTOK / 256, 256, 0, stream>>>(idx_i32, cursor, toklist);
    k_dw     <<<NUM_EMB, 64, 0, stream>>>(Ap, counts, offsets, toklist, dw);
    k_qst    <<<QELEMS / 1024, 256, 0, stream>>>(x, emb, idx_i32, out + 1, loss_acc);
    k_stats  <<<1, 256, 0, stream>>>(counts, cs, loss_acc, n_scal, out);
    k_final  <<<NUM_EMB, 256, 0, stream>>>(cs, emaw, counts, dw, n_scal,
                                           out + 4194306, out + 6291458, out + 6299650);
}

// Round 3
// 449.247 us; speedup vs baseline: 2.7702x; 1.2112x over previous
//
#include <hip/hip_runtime.h>
#include <hip/hip_bf16.h>
#include <math.h>

#define NUM_EMB 8192
#define EMB_DIM 256
#define NTOK    16384      // 16 * 32 * 32
#define HW      1024
#define QELEMS  4194304    // 16 * 256 * 1024
#define DECAY   0.99f
#define OMD     0.01f
#define COMMIT  0.25f
#define EPS_    1e-5f
#define MARGIN  0.5f       // approx-dist error sigma ~1.3e-2; 0.5 is ~38 sigma

typedef _Float16 h8 __attribute__((ext_vector_type(8)));
typedef float    f4 __attribute__((ext_vector_type(4)));

#define GLD16(gptr, lptr) \
  __builtin_amdgcn_global_load_lds((const __attribute__((address_space(1))) void*)(gptr), \
                                   (__attribute__((address_space(3))) void*)(lptr), 16, 0, 0)

// ---------------- k_prep: x->Ap(f16 hi)+xT(f32), emb->Bp(f16 hi), esq ----------------
// Ap fragment layout: [(mt*8+kc)*64+lane]*8 halves; token = mt*16+(lane&15),
// d = kc*32 + (lane>>4)*8 + j.   Bp analogous with code rows.
__global__ __launch_bounds__(256)
void k_prep(const float* __restrict__ x, const float* __restrict__ emb,
            _Float16* __restrict__ Ap, _Float16* __restrict__ Bp,
            float* __restrict__ xT, float* __restrict__ esq) {
    int bb = blockIdx.x;
    if (bb < 2048) {
        int g = bb * 256 + threadIdx.x;          // 0..524287
        int lane = g & 63;
        int kc = (g >> 6) & 7;
        int mt = g >> 9;                         // 0..1023
        int tok = mt * 16 + (lane & 15);
        int b = tok >> 10, hw = tok & 1023;
        int d0 = kc * 32 + (lane >> 4) * 8;
        const float* src = x + (size_t)b * 262144 + (size_t)d0 * 1024 + hw;
        h8 hi; float tmp[8];
        #pragma unroll
        for (int u = 0; u < 8; u++) {
            float v = src[(size_t)u * 1024];
            hi[u] = (_Float16)v;
            tmp[u] = v;
        }
        *(h8*)(Ap + ((size_t)(mt * 8 + kc) * 64 + lane) * 8) = hi;
        *(float4*)(xT + (size_t)tok * 256 + d0)     = *(float4*)(&tmp[0]);
        *(float4*)(xT + (size_t)tok * 256 + d0 + 4) = *(float4*)(&tmp[4]);
    } else if (bb < 3072) {
        int g = (bb - 2048) * 256 + threadIdx.x; // 0..262143
        int lane = g & 63;
        int kc = (g >> 6) & 7;
        int nt = g >> 9;                         // 0..511
        int n = nt * 16 + (lane & 15);
        int d0 = kc * 32 + (lane >> 4) * 8;
        const float* src = emb + (size_t)n * EMB_DIM + d0;
        h8 hi;
        #pragma unroll
        for (int u = 0; u < 8; u++) hi[u] = (_Float16)src[u];
        *(h8*)(Bp + ((size_t)(nt * 8 + kc) * 64 + lane) * 8) = hi;
    } else {
        int k = (bb - 3072) * 4 + (threadIdx.x >> 6);
        int lane = threadIdx.x & 63;
        const float* row = emb + (size_t)k * EMB_DIM;
        float4 v = *(const float4*)(row + lane * 4);
        float s = v.x * v.x + v.y * v.y + v.z * v.z + v.w * v.w;
        #pragma unroll
        for (int m = 32; m >= 1; m >>= 1) s += __shfl_xor(s, m);
        if (lane == 0) esq[k] = s;
    }
}

// ---------------- k_dist: single-pass f16 MFMA GEMM + top-2-per-slice epilogue ------
__global__ __launch_bounds__(256, 2)
void k_dist(const _Float16* __restrict__ Ap, const _Float16* __restrict__ Bp,
            const float* __restrict__ esq, float4* __restrict__ pairs) {
    __shared__ _Float16 Abuf[8 * 64 * 8];   // 8 KB
    __shared__ _Float16 Bbuf[8 * 64 * 8];   // 8 KB
    __shared__ float4 sv2[2][128];          // 4 KB

    const int tid  = threadIdx.x;
    const int lane = tid & 63;
    const int w    = tid >> 6;
    const int wm   = w >> 1, wn = w & 1;
    const int bN   = blockIdx.x & 63;
    const int bM   = blockIdx.x >> 6;
    const int m0   = bM * 128, n0 = bN * 128;

    f4 acc[4][4] = {};

    #pragma unroll 1
    for (int kc = 0; kc < 8; ++kc) {
        __syncthreads();
        const int t0 = w * 2;
        GLD16(Ap + ((size_t)((bM * 8 + t0)     * 8 + kc) * 64 + lane) * 8, Abuf + t0 * 512);
        GLD16(Ap + ((size_t)((bM * 8 + t0 + 1) * 8 + kc) * 64 + lane) * 8, Abuf + (t0 + 1) * 512);
        GLD16(Bp + ((size_t)((bN * 8 + t0)     * 8 + kc) * 64 + lane) * 8, Bbuf + t0 * 512);
        GLD16(Bp + ((size_t)((bN * 8 + t0 + 1) * 8 + kc) * 64 + lane) * 8, Bbuf + (t0 + 1) * 512);
        __syncthreads();

        h8 aF[4], bF[4];
        #pragma unroll
        for (int i = 0; i < 4; i++)
            aF[i] = *(const h8*)(Abuf + ((wm * 4 + i) * 64 + lane) * 8);
        #pragma unroll
        for (int j = 0; j < 4; j++)
            bF[j] = *(const h8*)(Bbuf + ((wn * 4 + j) * 64 + lane) * 8);
        #pragma unroll
        for (int i = 0; i < 4; i++)
            #pragma unroll
            for (int j = 0; j < 4; j++)
                acc[i][j] = __builtin_amdgcn_mfma_f32_16x16x32_f16(aF[i], bF[j], acc[i][j], 0, 0, 0);
    }

    // epilogue: approx dist = esq[n] - 2*dot; per-row top-2 over this wave's 64 codes
    float ev[4];
    #pragma unroll
    for (int j = 0; j < 4; j++) ev[j] = esq[n0 + wn * 64 + j * 16 + (lane & 15)];

    #pragma unroll
    for (int i = 0; i < 4; i++) {
        #pragma unroll
        for (int reg = 0; reg < 4; reg++) {
            float b1 = 3.4e38f, s1 = 3.4e38f;
            int b1i = 0x7fffffff, s1i = 0x7fffffff;
            #pragma unroll
            for (int j = 0; j < 4; j++) {
                float dv = fmaf(-2.0f, acc[i][j][reg], ev[j]);
                int ki = n0 + wn * 64 + j * 16 + (lane & 15);
                if (dv < b1 || (dv == b1 && ki < b1i)) { s1 = b1; s1i = b1i; b1 = dv; b1i = ki; }
                else if (dv < s1) { s1 = dv; s1i = ki; }
            }
            #pragma unroll
            for (int mask = 1; mask <= 8; mask <<= 1) {
                float ov  = __shfl_xor(b1, mask);  int oi  = __shfl_xor(b1i, mask);
                float ov2 = __shfl_xor(s1, mask);  int oi2 = __shfl_xor(s1i, mask);
                if (ov < b1 || (ov == b1 && oi < b1i)) {
                    float ns = b1; int nsi = b1i;
                    if (ov2 < ns) { ns = ov2; nsi = oi2; }
                    b1 = ov; b1i = oi; s1 = ns; s1i = nsi;
                } else if (ov < s1) { s1 = ov; s1i = oi; }
            }
            if ((lane & 15) == 0) {
                int r = wm * 64 + i * 16 + ((lane >> 4) << 2) + reg;
                sv2[wn][r] = make_float4(b1, __int_as_float(b1i), s1, __int_as_float(s1i));
            }
        }
    }
    __syncthreads();
    if (tid < 128) {
        float4 A = sv2[0][tid], C = sv2[1][tid];
        float a1 = A.x, a2 = A.z, c1 = C.x, c2 = C.z;
        int a1i = __float_as_int(A.y), a2i = __float_as_int(A.w);
        int c1i = __float_as_int(C.y), c2i = __float_as_int(C.w);
        float b, s; int bi, si;
        if (c1 < a1 || (c1 == a1 && c1i < a1i)) {
            b = c1; bi = c1i; s = a1; si = a1i;
            if (c2 < s) { s = c2; si = c2i; }
        } else {
            b = a1; bi = a1i; s = a2; si = a2i;
            if (c1 < s) { s = c1; si = c1i; }
        }
        pairs[(size_t)(m0 + tid) * 64 + bN] = make_float4(b, __int_as_float(bi), s, __int_as_float(si));
    }
}

// ---------------- k_refine: merge slices, exact fp32 over candidates ----------------
__global__ __launch_bounds__(256)
void k_refine(const float4* __restrict__ pairs, const float* __restrict__ xT,
              const float* __restrict__ emb, const float* __restrict__ esq,
              int* __restrict__ idx_i32, float* __restrict__ out_idxf,
              float* __restrict__ counts) {
    int lane = threadIdx.x & 63;
    int tok = blockIdx.x * 4 + (threadIdx.x >> 6);
    float4 p = pairs[(size_t)tok * 64 + lane];
    float v1 = p.x, v2 = p.z;
    int i1 = __float_as_int(p.y), i2 = __float_as_int(p.w);

    // global approx best (v1 <= v2 always)
    float bv = v1; int bi = i1;
    #pragma unroll
    for (int mask = 1; mask <= 32; mask <<= 1) {
        float ov = __shfl_xor(bv, mask); int oi = __shfl_xor(bi, mask);
        if (ov < bv || (ov == bv && oi < bi)) { bv = ov; bi = oi; }
    }
    float thresh = bv + MARGIN;
    float4 xv = *(const float4*)(xT + (size_t)tok * 256 + lane * 4);

    unsigned long long m1 = __ballot(v1 <= thresh);
    unsigned long long m2 = __ballot(v2 <= thresh);
    float bestd = 3.4e38f; int besti = 0x7fffffff;
    while (m1 | m2) {
        int k;
        if (m1) { int l = __ffsll(m1) - 1; m1 &= m1 - 1; k = __shfl(i1, l); }
        else    { int l = __ffsll(m2) - 1; m2 &= m2 - 1; k = __shfl(i2, l); }
        float4 e4 = *(const float4*)(emb + (size_t)k * EMB_DIM + lane * 4);
        float d = xv.x * e4.x + xv.y * e4.y + xv.z * e4.z + xv.w * e4.w;
        #pragma unroll
        for (int mask = 1; mask <= 32; mask <<= 1) d += __shfl_xor(d, mask);
        float dist = esq[k] - 2.0f * d;
        if (dist < bestd || (dist == bestd && k < besti)) { bestd = dist; besti = k; }
    }
    if (lane == 0) {
        idx_i32[tok] = besti;
        out_idxf[tok] = (float)besti;
        atomicAdd(&counts[besti], 1.0f);
    }
}

// ---------------- k_ivt: single-block prefix sum + token scatter ----------------
__global__ __launch_bounds__(256)
void k_ivt(const float* __restrict__ counts, const int* __restrict__ idx_i32,
           int* __restrict__ offsets, int* __restrict__ toklist) {
    __shared__ int part[256];
    __shared__ int cur[NUM_EMB];
    int t = threadIdx.x;
    int base = t * 32;
    int loc[32]; int s = 0;
    #pragma unroll
    for (int u = 0; u < 32; u++) { loc[u] = s; s += (int)counts[base + u]; }
    part[t] = s;
    __syncthreads();
    for (int off = 1; off < 256; off <<= 1) {
        int add = (t >= off) ? part[t - off] : 0;
        __syncthreads();
        part[t] += add;
        __syncthreads();
    }
    int excl = part[t] - s;
    #pragma unroll
    for (int u = 0; u < 32; u++) {
        int o = excl + loc[u];
        offsets[base + u] = o;
        cur[base + u] = o;
    }
    __syncthreads();
    for (int n = t; n < NTOK; n += 256) {
        int k = idx_i32[n];
        int p = atomicAdd(&cur[k], 1);
        toklist[p] = n;
    }
}

// ---------------- k_qst: straight-through output + commitment loss ----------------
__global__ __launch_bounds__(256)
void k_qst(const float* __restrict__ x, const float* __restrict__ emb,
           const int* __restrict__ idx_i32, float* __restrict__ out_qst,
           float* __restrict__ loss_acc) {
    int t = blockIdx.x * 256 + threadIdx.x;
    int e = t * 4;
    int b = e >> 18;
    int r = e & 262143;
    int d = r >> 10;
    int hw = r & 1023;
    int nb = (b << 10) | hw;
    float4 xv = *(const float4*)(x + e);
    float q0 = emb[(size_t)idx_i32[nb + 0] * EMB_DIM + d];
    float q1 = emb[(size_t)idx_i32[nb + 1] * EMB_DIM + d];
    float q2 = emb[(size_t)idx_i32[nb + 2] * EMB_DIM + d];
    float q3 = emb[(size_t)idx_i32[nb + 3] * EMB_DIM + d];
    float d0 = q0 - xv.x, d1 = q1 - xv.y, d2 = q2 - xv.z, d3 = q3 - xv.w;
    float4 o; o.x = xv.x + d0; o.y = xv.y + d1; o.z = xv.z + d2; o.w = xv.w + d3;
    *(float4*)(out_qst + e) = o;

    float sq = d0 * d0 + d1 * d1 + d2 * d2 + d3 * d3;
    #pragma unroll
    for (int m = 32; m >= 1; m >>= 1) sq += __shfl_xor(sq, m);
    __shared__ float wsum[4];
    int lane = threadIdx.x & 63, wid = threadIdx.x >> 6;
    if (lane == 0) wsum[wid] = sq;
    __syncthreads();
    if (threadIdx.x == 0)
        atomicAdd(loss_acc, wsum[0] + wsum[1] + wsum[2] + wsum[3]);
}

// ---------------- k_stats: n, perplexity, loss (single block) ----------------
__global__ __launch_bounds__(256)
void k_stats(const float* __restrict__ counts, const float* __restrict__ cs,
             const float* __restrict__ loss_acc,
             float* __restrict__ n_out, float* __restrict__ out) {
    int tid = threadIdx.x;
    float s1 = 0.0f, s2 = 0.0f;
    for (int k = tid; k < NUM_EMB; k += 256) {
        float c = counts[k];
        s1 += cs[k] * DECAY + OMD * c;
        float p = c / (float)NTOK;
        s2 += p * logf(p + 1e-10f);
    }
    #pragma unroll
    for (int m = 32; m >= 1; m >>= 1) {
        s1 += __shfl_xor(s1, m);
        s2 += __shfl_xor(s2, m);
    }
    __shared__ float w1[4], w2[4];
    int lane = tid & 63, wid = tid >> 6;
    if (lane == 0) { w1[wid] = s1; w2[wid] = s2; }
    __syncthreads();
    if (tid == 0) {
        float n  = w1[0] + w1[1] + w1[2] + w1[3];
        float e2 = w2[0] + w2[1] + w2[2] + w2[3];
        n_out[0] = n;
        out[4194305] = expf(-e2);                        // perplexity
        out[0] = COMMIT * loss_acc[0] / (float)QELEMS;   // loss
    }
}

// ---------------- k_dw_final: per-code dw row-sum fused with EMA outputs ------------
__global__ __launch_bounds__(64)
void k_dw_final(const float* __restrict__ xT, const float* __restrict__ counts,
                const int* __restrict__ offsets, const int* __restrict__ toklist,
                const float* __restrict__ cs, const float* __restrict__ emaw,
                const float* __restrict__ n_in,
                float* __restrict__ out_emb, float* __restrict__ out_cs,
                float* __restrict__ out_emaw) {
    int k = blockIdx.x;
    int lane = threadIdx.x;
    int c = (int)counts[k];
    int off = offsets[k];
    float a0 = 0, a1 = 0, a2 = 0, a3 = 0;
    for (int t = 0; t < c; t++) {
        int tok = toklist[off + t];
        float4 v = *(const float4*)(xT + (size_t)tok * 256 + lane * 4);
        a0 += v.x; a1 += v.y; a2 += v.z; a3 += v.w;
    }
    float n = n_in[0];
    float pre  = cs[k] * DECAY + OMD * counts[k];
    float cssm = (pre + EPS_) / (n + (float)NUM_EMB * EPS_) * n;
    size_t o = (size_t)k * EMB_DIM + lane * 4;
    float4 ew = *(const float4*)(emaw + o);
    float4 wv;
    wv.x = ew.x * DECAY + OMD * a0;
    wv.y = ew.y * DECAY + OMD * a1;
    wv.z = ew.z * DECAY + OMD * a2;
    wv.w = ew.w * DECAY + OMD * a3;
    *(float4*)(out_emaw + o) = wv;
    float4 ob; ob.x = wv.x / cssm; ob.y = wv.y / cssm; ob.z = wv.z / cssm; ob.w = wv.w / cssm;
    *(float4*)(out_emb + o) = ob;
    if (lane == 0) out_cs[k] = cssm;
}

extern "C" void kernel_launch(void* const* d_in, const int* in_sizes, int n_in,
                              void* d_out, int out_size, void* d_ws, size_t ws_size,
                              hipStream_t stream) {
    const float* x    = (const float*)d_in[0];   // [16,256,32,32]
    const float* emb  = (const float*)d_in[1];   // [8192,256]
    const float* cs   = (const float*)d_in[2];   // [8192]
    const float* emaw = (const float*)d_in[3];   // [8192,256]
    float* out = (float*)d_out;

    // workspace layout (bytes)
    char* W = (char*)d_ws;
    _Float16* Ap    = (_Float16*)(W);             //  8,388,608
    _Float16* Bp    = (_Float16*)(W + 8388608);   //  4,194,304
    float*  xT      = (float*) (W + 12582912);    // 16,777,216
    float4* pairs   = (float4*)(W + 29360128);    // 16,777,216
    float* esq      = (float*) (W + 46137344);    //     32,768
    float* counts   = (float*) (W + 46170112);    //     32,768
    float* loss_acc = (float*) (W + 46202880);    //          4
    float* n_scal   = (float*) (W + 46202884);    //          4
    int*   offsets  = (int*)   (W + 46202888);    //     32,768
    int*   toklist  = (int*)   (W + 46235656);    //     65,536
    int*   idx_i32  = (int*)   (W + 46301192);    //     65,536  (end ~44.2 MB)

    hipMemsetAsync(counts, 0, 32768 + 8, stream);   // counts + loss_acc + n_scal

    k_prep    <<<5120, 256, 0, stream>>>(x, emb, Ap, Bp, xT, esq);
    k_dist    <<<8192, 256, 0, stream>>>(Ap, Bp, esq, pairs);
    k_refine  <<<4096, 256, 0, stream>>>(pairs, xT, emb, esq, idx_i32,
                                         out + 8396802, counts);
    k_ivt     <<<1, 256, 0, stream>>>(counts, idx_i32, offsets, toklist);
    k_qst     <<<QELEMS / 1024, 256, 0, stream>>>(x, emb, idx_i32, out + 1, loss_acc);
    k_stats   <<<1, 256, 0, stream>>>(counts, cs, loss_acc, n_scal, out);
    k_dw_final<<<NUM_EMB, 64, 0, stream>>>(xT, counts, offsets, toklist, cs, emaw,
                                           n_scal, out + 4194306, out + 6291458,
                                           out + 6299650);
}

// Round 4
// 426.367 us; speedup vs baseline: 2.9189x; 1.0537x over previous
//
#include <hip/hip_runtime.h>
#include <hip/hip_bf16.h>
#include <math.h>

#define NUM_EMB 8192
#define EMB_DIM 256
#define NTOK    16384      // 16 * 32 * 32
#define HW      1024
#define QELEMS  4194304    // 16 * 256 * 1024
#define DECAY   0.99f
#define OMD     0.01f
#define COMMIT  0.25f
#define EPS_    1e-5f
#define MARGIN  0.6f
#define NSLICE  16         // codes per slice = 512

typedef _Float16 h8 __attribute__((ext_vector_type(8)));
typedef float    f4 __attribute__((ext_vector_type(4)));

#define GLD16(gptr, lptr) \
  __builtin_amdgcn_global_load_lds((const __attribute__((address_space(1))) void*)(gptr), \
                                   (__attribute__((address_space(3))) void*)(lptr), 16, 0, 0)

// ---------------- k_prep: x->Ap(f16)+xT(f32), emb->Bp(f16), esq ----------------
// Ap fragment layout: [(mt*8+kc)*64+lane]*8 halves; token = mt*16+(lane&15),
// d = kc*32 + (lane>>4)*8 + j.   Bp analogous with code rows.
__global__ __launch_bounds__(256)
void k_prep(const float* __restrict__ x, const float* __restrict__ emb,
            _Float16* __restrict__ Ap, _Float16* __restrict__ Bp,
            float* __restrict__ xT, float* __restrict__ esq) {
    int bb = blockIdx.x;
    if (bb < 2048) {
        int g = bb * 256 + threadIdx.x;
        int lane = g & 63;
        int kc = (g >> 6) & 7;
        int mt = g >> 9;                         // 0..1023
        int tok = mt * 16 + (lane & 15);
        int b = tok >> 10, hw = tok & 1023;
        int d0 = kc * 32 + (lane >> 4) * 8;
        const float* src = x + (size_t)b * 262144 + (size_t)d0 * 1024 + hw;
        h8 hi; float tmp[8];
        #pragma unroll
        for (int u = 0; u < 8; u++) {
            float v = src[(size_t)u * 1024];
            hi[u] = (_Float16)v;
            tmp[u] = v;
        }
        *(h8*)(Ap + ((size_t)(mt * 8 + kc) * 64 + lane) * 8) = hi;
        *(float4*)(xT + (size_t)tok * 256 + d0)     = *(float4*)(&tmp[0]);
        *(float4*)(xT + (size_t)tok * 256 + d0 + 4) = *(float4*)(&tmp[4]);
    } else if (bb < 3072) {
        int g = (bb - 2048) * 256 + threadIdx.x;
        int lane = g & 63;
        int kc = (g >> 6) & 7;
        int nt = g >> 9;                         // 0..511
        int n = nt * 16 + (lane & 15);
        int d0 = kc * 32 + (lane >> 4) * 8;
        const float* src = emb + (size_t)n * EMB_DIM + d0;
        h8 hi;
        #pragma unroll
        for (int u = 0; u < 8; u++) hi[u] = (_Float16)src[u];
        *(h8*)(Bp + ((size_t)(nt * 8 + kc) * 64 + lane) * 8) = hi;
    } else {
        int k = (bb - 3072) * 4 + (threadIdx.x >> 6);
        int lane = threadIdx.x & 63;
        const float* row = emb + (size_t)k * EMB_DIM;
        float4 v = *(const float4*)(row + lane * 4);
        float s = v.x * v.x + v.y * v.y + v.z * v.z + v.w * v.w;
        #pragma unroll
        for (int m = 32; m >= 1; m >>= 1) s += __shfl_xor(s, m);
        if (lane == 0) esq[k] = s;
    }
}

// ---------------- k_dist: A-resident MFMA GEMM, running per-lane top-2 --------------
// grid = 128 M-tiles x 16 N-slices (512 codes). A tile (128x256 f16 = 64KB) LDS-
// resident; loop 4 n-subtiles of 128 codes; cross-lane merge ONCE at block end.
__global__ __launch_bounds__(256, 2)
void k_dist(const _Float16* __restrict__ Ap, const _Float16* __restrict__ Bp,
            const float* __restrict__ esq, float4* __restrict__ pairs) {
    __shared__ _Float16 Abuf[8 * 8 * 64 * 8];   // 64 KB
    __shared__ _Float16 Bbuf[8 * 64 * 8];       // 8 KB (also reused as merge buf)

    const int tid  = threadIdx.x;
    const int lane = tid & 63;
    const int w    = tid >> 6;
    const int wm   = w >> 1, wn = w & 1;
    const int bM   = blockIdx.x >> 4;           // 0..127
    const int bS   = blockIdx.x & 15;           // 0..15
    const int m0   = bM * 128;

    // stage full A tile: contiguous 64 KB from Ap
    #pragma unroll
    for (int s = 0; s < 16; s++) {
        int seg = w * 16 + s;
        GLD16(Ap + (size_t)bM * 32768 + (size_t)seg * 512 + lane * 8, Abuf + seg * 512);
    }

    float b1[16], s1[16];
    int   b1i[16], s1i[16];
    #pragma unroll
    for (int r = 0; r < 16; r++) {
        b1[r] = 3.4e38f; s1[r] = 3.4e38f;
        b1i[r] = 0x7fffffff; s1i[r] = 0x7fffffff;
    }

    #pragma unroll 1
    for (int nt = 0; nt < 4; ++nt) {
        const int n0 = bS * 512 + nt * 128;
        f4 acc[4][4] = {};
        #pragma unroll 1
        for (int kc = 0; kc < 8; ++kc) {
            __syncthreads();
            {
                int t0 = w * 2;
                GLD16(Bp + ((size_t)((bS * 32 + nt * 8 + t0)     * 8 + kc) * 64 + lane) * 8, Bbuf + t0 * 512);
                GLD16(Bp + ((size_t)((bS * 32 + nt * 8 + t0 + 1) * 8 + kc) * 64 + lane) * 8, Bbuf + (t0 + 1) * 512);
            }
            __syncthreads();
            h8 aF[4], bF[4];
            #pragma unroll
            for (int i = 0; i < 4; i++)
                aF[i] = *(const h8*)(Abuf + (((wm * 4 + i) * 8 + kc) * 64 + lane) * 8);
            #pragma unroll
            for (int j = 0; j < 4; j++)
                bF[j] = *(const h8*)(Bbuf + ((wn * 4 + j) * 64 + lane) * 8);
            #pragma unroll
            for (int i = 0; i < 4; i++)
                #pragma unroll
                for (int j = 0; j < 4; j++)
                    acc[i][j] = __builtin_amdgcn_mfma_f32_16x16x32_f16(aF[i], bF[j], acc[i][j], 0, 0, 0);
        }
        // running per-lane top-2 update (no shuffles)
        float ev[4];
        #pragma unroll
        for (int j = 0; j < 4; j++) ev[j] = esq[n0 + wn * 64 + j * 16 + (lane & 15)];
        #pragma unroll
        for (int i = 0; i < 4; i++) {
            #pragma unroll
            for (int reg = 0; reg < 4; reg++) {
                const int r = i * 4 + reg;
                #pragma unroll
                for (int j = 0; j < 4; j++) {
                    float dv = fmaf(-2.0f, acc[i][j][reg], ev[j]);
                    int ki = n0 + wn * 64 + j * 16 + (lane & 15);
                    if (dv < b1[r]) { s1[r] = b1[r]; s1i[r] = b1i[r]; b1[r] = dv; b1i[r] = ki; }
                    else if (dv < s1[r]) { s1[r] = dv; s1i[r] = ki; }
                }
            }
        }
    }

    // cross-lane exact top-2 merge, once per block
    float4* sv2 = (float4*)Bbuf;    // 2 x 128 float4 = 4 KB, Bbuf is dead
    #pragma unroll
    for (int i = 0; i < 4; i++) {
        #pragma unroll
        for (int reg = 0; reg < 4; reg++) {
            const int rr = i * 4 + reg;
            float b = b1[rr], s = s1[rr];
            int bi = b1i[rr], si = s1i[rr];
            #pragma unroll
            for (int mask = 1; mask <= 8; mask <<= 1) {
                float ov  = __shfl_xor(b, mask);  int oi  = __shfl_xor(bi, mask);
                float ov2 = __shfl_xor(s, mask);  int oi2 = __shfl_xor(si, mask);
                if (ov < b || (ov == b && oi < bi)) {
                    float ns = b; int nsi = bi;
                    if (ov2 < ns) { ns = ov2; nsi = oi2; }
                    b = ov; bi = oi; s = ns; si = nsi;
                } else if (ov < s) { s = ov; si = oi; }
            }
            if (i == 0 && reg == 0) __syncthreads();   // protect Bbuf reuse (once)
            if ((lane & 15) == 0) {
                int r = wm * 64 + i * 16 + ((lane >> 4) << 2) + reg;
                sv2[wn * 128 + r] = make_float4(b, __int_as_float(bi), s, __int_as_float(si));
            }
        }
    }
    __syncthreads();
    if (tid < 128) {
        float4 A = sv2[tid], C = sv2[128 + tid];
        float a1 = A.x, a2 = A.z, c1 = C.x, c2 = C.z;
        int a1i = __float_as_int(A.y), a2i = __float_as_int(A.w);
        int c1i = __float_as_int(C.y), c2i = __float_as_int(C.w);
        float b, s; int bi, si;
        if (c1 < a1 || (c1 == a1 && c1i < a1i)) {
            b = c1; bi = c1i; s = a1; si = a1i;
            if (c2 < s) { s = c2; si = c2i; }
        } else {
            b = a1; bi = a1i; s = a2; si = a2i;
            if (c1 < s) { s = c1; si = c1i; }
        }
        pairs[(size_t)(m0 + tid) * NSLICE + bS] = make_float4(b, __int_as_float(bi), s, __int_as_float(si));
    }
}

// ---------------- k_refine: slice merge + exact fp32 argmin + fused q_st/loss -------
__global__ __launch_bounds__(256)
void k_refine(const float4* __restrict__ pairs, const float* __restrict__ xT,
              const float* __restrict__ emb, const float* __restrict__ esq,
              int* __restrict__ idx_i32, float* __restrict__ out_idxf,
              float* __restrict__ counts, float* __restrict__ out_qst,
              float* __restrict__ loss_parts) {
    int lane = threadIdx.x & 63;
    int wid  = threadIdx.x >> 6;
    int tok  = blockIdx.x * 4 + wid;

    float4 p = (lane < NSLICE) ? pairs[(size_t)tok * NSLICE + lane]
                               : make_float4(3.4e38f, __int_as_float(0x7fffffff),
                                             3.4e38f, __int_as_float(0x7fffffff));
    float v1 = p.x, v2 = p.z;
    int i1 = __float_as_int(p.y), i2 = __float_as_int(p.w);

    // global approx best across all lanes (INF elsewhere)
    float bv = v1; int bi = i1;
    #pragma unroll
    for (int mask = 1; mask <= 32; mask <<= 1) {
        float ov = __shfl_xor(bv, mask); int oi = __shfl_xor(bi, mask);
        if (ov < bv || (ov == bv && oi < bi)) { bv = ov; bi = oi; }
    }
    float thresh = bv + MARGIN;
    float4 xv = *(const float4*)(xT + (size_t)tok * 256 + lane * 4);

    unsigned long long m1 = __ballot(v1 <= thresh);
    unsigned long long m2 = __ballot(v2 <= thresh);
    float bestd = 3.4e38f; int besti = 0x7fffffff;
    while (m1 | m2) {
        int k;
        if (m1) { int l = __ffsll(m1) - 1; m1 &= m1 - 1; k = __shfl(i1, l); }
        else    { int l = __ffsll(m2) - 1; m2 &= m2 - 1; k = __shfl(i2, l); }
        float4 e4 = *(const float4*)(emb + (size_t)k * EMB_DIM + lane * 4);
        float d = xv.x * e4.x + xv.y * e4.y + xv.z * e4.z + xv.w * e4.w;
        #pragma unroll
        for (int mask = 1; mask <= 32; mask <<= 1) d += __shfl_xor(d, mask);
        float dist = esq[k] - 2.0f * d;
        if (dist < bestd || (dist == bestd && k < besti)) { bestd = dist; besti = k; }
    }

    // fused straight-through output + loss (coalesced reads; strided 4B writes -> L2)
    float4 e4 = *(const float4*)(emb + (size_t)besti * EMB_DIM + lane * 4);
    float d0 = e4.x - xv.x, d1 = e4.y - xv.y, d2 = e4.z - xv.z, d3 = e4.w - xv.w;
    int b = tok >> 10, hw = tok & 1023;
    float* ob = out_qst + (size_t)b * 262144 + hw;
    ob[(size_t)(lane * 4 + 0) * 1024] = xv.x + d0;
    ob[(size_t)(lane * 4 + 1) * 1024] = xv.y + d1;
    ob[(size_t)(lane * 4 + 2) * 1024] = xv.z + d2;
    ob[(size_t)(lane * 4 + 3) * 1024] = xv.w + d3;

    float sq = d0 * d0 + d1 * d1 + d2 * d2 + d3 * d3;
    #pragma unroll
    for (int mask = 1; mask <= 32; mask <<= 1) sq += __shfl_xor(sq, mask);

    __shared__ float wsum[4];
    if (lane == 0) {
        wsum[wid] = sq;
        idx_i32[tok] = besti;
        out_idxf[tok] = (float)besti;
        atomicAdd(&counts[besti], 1.0f);
    }
    __syncthreads();
    if (threadIdx.x == 0)
        loss_parts[blockIdx.x] = wsum[0] + wsum[1] + wsum[2] + wsum[3];
}

// ---------------- k_ivt_stats: prefix sum + scatter + n/perplexity/loss -------------
__global__ __launch_bounds__(256)
void k_ivt_stats(const float* __restrict__ counts, const int* __restrict__ idx_i32,
                 const float* __restrict__ cs, const float* __restrict__ loss_parts,
                 int* __restrict__ offsets, int* __restrict__ toklist,
                 float* __restrict__ n_out, float* __restrict__ out) {
    __shared__ int part[256];
    __shared__ int cur[NUM_EMB];
    int t = threadIdx.x;
    int base = t * 32;
    int loc[32]; int s = 0;
    #pragma unroll
    for (int u = 0; u < 32; u++) { loc[u] = s; s += (int)counts[base + u]; }
    part[t] = s;
    __syncthreads();
    for (int off = 1; off < 256; off <<= 1) {
        int add = (t >= off) ? part[t - off] : 0;
        __syncthreads();
        part[t] += add;
        __syncthreads();
    }
    int excl = part[t] - s;
    #pragma unroll
    for (int u = 0; u < 32; u++) {
        int o = excl + loc[u];
        offsets[base + u] = o;
        cur[base + u] = o;
    }
    __syncthreads();
    for (int n = t; n < NTOK; n += 256) {
        int k = idx_i32[n];
        int p = atomicAdd(&cur[k], 1);
        toklist[p] = n;
    }

    // stats
    float s1 = 0.0f, s2 = 0.0f, s3 = 0.0f;
    for (int k = t; k < NUM_EMB; k += 256) {
        float c = counts[k];
        s1 += cs[k] * DECAY + OMD * c;
        float pb = c / (float)NTOK;
        s2 += pb * logf(pb + 1e-10f);
    }
    for (int k = t; k < 4096; k += 256) s3 += loss_parts[k];
    #pragma unroll
    for (int m = 32; m >= 1; m >>= 1) {
        s1 += __shfl_xor(s1, m);
        s2 += __shfl_xor(s2, m);
        s3 += __shfl_xor(s3, m);
    }
    __shared__ float w1[4], w2[4], w3[4];
    int lane = t & 63, wid = t >> 6;
    if (lane == 0) { w1[wid] = s1; w2[wid] = s2; w3[wid] = s3; }
    __syncthreads();
    if (t == 0) {
        float n  = w1[0] + w1[1] + w1[2] + w1[3];
        float e2 = w2[0] + w2[1] + w2[2] + w2[3];
        float ls = w3[0] + w3[1] + w3[2] + w3[3];
        n_out[0] = n;
        out[4194305] = expf(-e2);                 // perplexity
        out[0] = COMMIT * ls / (float)QELEMS;     // loss
    }
}

// ---------------- k_dw_final: per-code dw row-sum fused with EMA outputs ------------
__global__ __launch_bounds__(64)
void k_dw_final(const float* __restrict__ xT, const float* __restrict__ counts,
                const int* __restrict__ offsets, const int* __restrict__ toklist,
                const float* __restrict__ cs, const float* __restrict__ emaw,
                const float* __restrict__ n_in,
                float* __restrict__ out_emb, float* __restrict__ out_cs,
                float* __restrict__ out_emaw) {
    int k = blockIdx.x;
    int lane = threadIdx.x;
    int c = (int)counts[k];
    int off = offsets[k];
    float a0 = 0, a1 = 0, a2 = 0, a3 = 0;
    for (int t = 0; t < c; t++) {
        int tok = toklist[off + t];
        float4 v = *(const float4*)(xT + (size_t)tok * 256 + lane * 4);
        a0 += v.x; a1 += v.y; a2 += v.z; a3 += v.w;
    }
    float n = n_in[0];
    float pre  = cs[k] * DECAY + OMD * counts[k];
    float cssm = (pre + EPS_) / (n + (float)NUM_EMB * EPS_) * n;
    size_t o = (size_t)k * EMB_DIM + lane * 4;
    float4 ew = *(const float4*)(emaw + o);
    float4 wv;
    wv.x = ew.x * DECAY + OMD * a0;
    wv.y = ew.y * DECAY + OMD * a1;
    wv.z = ew.z * DECAY + OMD * a2;
    wv.w = ew.w * DECAY + OMD * a3;
    *(float4*)(out_emaw + o) = wv;
    float4 obv; obv.x = wv.x / cssm; obv.y = wv.y / cssm; obv.z = wv.z / cssm; obv.w = wv.w / cssm;
    *(float4*)(out_emb + o) = obv;
    if (lane == 0) out_cs[k] = cssm;
}

extern "C" void kernel_launch(void* const* d_in, const int* in_sizes, int n_in,
                              void* d_out, int out_size, void* d_ws, size_t ws_size,
                              hipStream_t stream) {
    const float* x    = (const float*)d_in[0];   // [16,256,32,32]
    const float* emb  = (const float*)d_in[1];   // [8192,256]
    const float* cs   = (const float*)d_in[2];   // [8192]
    const float* emaw = (const float*)d_in[3];   // [8192,256]
    float* out = (float*)d_out;

    // workspace layout (bytes)
    char* W = (char*)d_ws;
    _Float16* Ap      = (_Float16*)(W);             //  8,388,608
    _Float16* Bp      = (_Float16*)(W + 8388608);   //  4,194,304
    float*  xT        = (float*) (W + 12582912);    // 16,777,216
    float4* pairs     = (float4*)(W + 29360128);    //  4,194,304
    float* esq        = (float*) (W + 33554432);    //     32,768
    float* counts     = (float*) (W + 33587200);    //     32,768
    float* loss_parts = (float*) (W + 33619968);    //     16,384
    float* n_scal     = (float*) (W + 33636352);    //          4
    int*   offsets    = (int*)   (W + 33636356);    //     32,768
    int*   toklist    = (int*)   (W + 33669124);    //     65,536
    int*   idx_i32    = (int*)   (W + 33734660);    //     65,536

    hipMemsetAsync(counts, 0, 32768, stream);

    k_prep     <<<5120, 256, 0, stream>>>(x, emb, Ap, Bp, xT, esq);
    k_dist     <<<2048, 256, 0, stream>>>(Ap, Bp, esq, pairs);
    k_refine   <<<4096, 256, 0, stream>>>(pairs, xT, emb, esq, idx_i32,
                                          out + 8396802, counts, out + 1, loss_parts);
    k_ivt_stats<<<1, 256, 0, stream>>>(counts, idx_i32, cs, loss_parts,
                                       offsets, toklist, n_scal, out);
    k_dw_final <<<NUM_EMB, 64, 0, stream>>>(xT, counts, offsets, toklist, cs, emaw,
                                            n_scal, out + 4194306, out + 6291458,
                                            out + 6299650);
}

// Round 5
// 405.721 us; speedup vs baseline: 3.0674x; 1.0509x over previous
//
#include <hip/hip_runtime.h>
#include <hip/hip_bf16.h>
#include <math.h>

#define NUM_EMB 8192
#define EMB_DIM 256
#define NTOK    16384      // 16 * 32 * 32
#define HW      1024
#define QELEMS  4194304    // 16 * 256 * 1024
#define DECAY   0.99f
#define OMD     0.01f
#define COMMIT  0.25f
#define EPS_    1e-5f
#define MARGIN  0.6f
#define NSLICE  16         // codes per slice = 512

typedef _Float16 h8 __attribute__((ext_vector_type(8)));
typedef float    f4 __attribute__((ext_vector_type(4)));

#define GLD16(gptr, lptr) \
  __builtin_amdgcn_global_load_lds((const __attribute__((address_space(1))) void*)(gptr), \
                                   (__attribute__((address_space(3))) void*)(lptr), 16, 0, 0)

// ---------------- k_prep: x->Ap(f16)+xT(f32), emb->Bp(f16), esq ----------------
// Ap fragment layout: [(mt*8+kc)*64+lane]*8 halves; token = mt*16+(lane&15),
// d = kc*32 + (lane>>4)*8 + j.   Bp analogous with code rows.
__global__ __launch_bounds__(256)
void k_prep(const float* __restrict__ x, const float* __restrict__ emb,
            _Float16* __restrict__ Ap, _Float16* __restrict__ Bp,
            float* __restrict__ xT, float* __restrict__ esq) {
    int bb = blockIdx.x;
    if (bb < 2048) {
        int g = bb * 256 + threadIdx.x;
        int lane = g & 63;
        int kc = (g >> 6) & 7;
        int mt = g >> 9;                         // 0..1023
        int tok = mt * 16 + (lane & 15);
        int b = tok >> 10, hw = tok & 1023;
        int d0 = kc * 32 + (lane >> 4) * 8;
        const float* src = x + (size_t)b * 262144 + (size_t)d0 * 1024 + hw;
        h8 hi; float tmp[8];
        #pragma unroll
        for (int u = 0; u < 8; u++) {
            float v = src[(size_t)u * 1024];
            hi[u] = (_Float16)v;
            tmp[u] = v;
        }
        *(h8*)(Ap + ((size_t)(mt * 8 + kc) * 64 + lane) * 8) = hi;
        *(float4*)(xT + (size_t)tok * 256 + d0)     = *(float4*)(&tmp[0]);
        *(float4*)(xT + (size_t)tok * 256 + d0 + 4) = *(float4*)(&tmp[4]);
    } else if (bb < 3072) {
        int g = (bb - 2048) * 256 + threadIdx.x;
        int lane = g & 63;
        int kc = (g >> 6) & 7;
        int nt = g >> 9;                         // 0..511
        int n = nt * 16 + (lane & 15);
        int d0 = kc * 32 + (lane >> 4) * 8;
        const float* src = emb + (size_t)n * EMB_DIM + d0;
        h8 hi;
        #pragma unroll
        for (int u = 0; u < 8; u++) hi[u] = (_Float16)src[u];
        *(h8*)(Bp + ((size_t)(nt * 8 + kc) * 64 + lane) * 8) = hi;
    } else {
        int k = (bb - 3072) * 4 + (threadIdx.x >> 6);
        int lane = threadIdx.x & 63;
        const float* row = emb + (size_t)k * EMB_DIM;
        float4 v = *(const float4*)(row + lane * 4);
        float s = v.x * v.x + v.y * v.y + v.z * v.z + v.w * v.w;
        #pragma unroll
        for (int m = 32; m >= 1; m >>= 1) s += __shfl_xor(s, m);
        if (lane == 0) esq[k] = s;
    }
}

// ---------------- k_dist: barrier-free MFMA GEMM; A in LDS, B global->VGPR ----------
// grid = 16 N-slices (bS major) x 128 M-tiles. A tile (128x256 f16 = 64KB) staged
// once (1 barrier); kc-loop has NO barriers: B fragments stream global->VGPR.
__global__ __launch_bounds__(256, 2)
void k_dist(const _Float16* __restrict__ Ap, const _Float16* __restrict__ Bp,
            const float* __restrict__ esq, float4* __restrict__ pairs) {
    __shared__ _Float16 Abuf[8 * 8 * 64 * 8];   // 64 KB
    __shared__ float4 sv2[256];                 // 4 KB merge buffer

    const int tid  = threadIdx.x;
    const int lane = tid & 63;
    const int w    = tid >> 6;
    const int wm   = w >> 1, wn = w & 1;
    const int bS   = blockIdx.x >> 7;           // 0..15  (slice-major for L2 reuse)
    const int bM   = blockIdx.x & 127;          // 0..127
    const int m0   = bM * 128;

    // stage full A tile once: contiguous 64 KB from Ap
    #pragma unroll
    for (int s = 0; s < 16; s++) {
        int seg = w * 16 + s;
        GLD16(Ap + (size_t)bM * 32768 + (size_t)seg * 512 + lane * 8, Abuf + seg * 512);
    }

    float b1[16], s1[16];
    int   b1i[16], s1i[16];
    #pragma unroll
    for (int r = 0; r < 16; r++) {
        b1[r] = 3.4e38f; s1[r] = 3.4e38f;
        b1i[r] = 0x7fffffff; s1i[r] = 0x7fffffff;
    }

    __syncthreads();   // the only staging barrier

    #pragma unroll 1
    for (int nt = 0; nt < 4; ++nt) {
        const int n0 = bS * 512 + nt * 128;
        f4 acc[4][4] = {};
        #pragma unroll 2
        for (int kc = 0; kc < 8; ++kc) {
            h8 aF[4], bF[4];
            #pragma unroll
            for (int j = 0; j < 4; j++)
                bF[j] = *(const h8*)(Bp + ((size_t)((bS * 32 + nt * 8 + wn * 4 + j) * 8 + kc) * 64 + lane) * 8);
            #pragma unroll
            for (int i = 0; i < 4; i++)
                aF[i] = *(const h8*)(Abuf + (((wm * 4 + i) * 8 + kc) * 64 + lane) * 8);
            #pragma unroll
            for (int i = 0; i < 4; i++)
                #pragma unroll
                for (int j = 0; j < 4; j++)
                    acc[i][j] = __builtin_amdgcn_mfma_f32_16x16x32_f16(aF[i], bF[j], acc[i][j], 0, 0, 0);
        }
        // running per-lane top-2 update (no cross-lane ops)
        float ev[4];
        #pragma unroll
        for (int j = 0; j < 4; j++) ev[j] = esq[n0 + wn * 64 + j * 16 + (lane & 15)];
        #pragma unroll
        for (int i = 0; i < 4; i++) {
            #pragma unroll
            for (int reg = 0; reg < 4; reg++) {
                const int r = i * 4 + reg;
                #pragma unroll
                for (int j = 0; j < 4; j++) {
                    float dv = fmaf(-2.0f, acc[i][j][reg], ev[j]);
                    int ki = n0 + wn * 64 + j * 16 + (lane & 15);
                    if (dv < b1[r]) { s1[r] = b1[r]; s1i[r] = b1i[r]; b1[r] = dv; b1i[r] = ki; }
                    else if (dv < s1[r]) { s1[r] = dv; s1i[r] = ki; }
                }
            }
        }
    }

    // cross-lane exact top-2 merge, once per block
    #pragma unroll
    for (int i = 0; i < 4; i++) {
        #pragma unroll
        for (int reg = 0; reg < 4; reg++) {
            const int rr = i * 4 + reg;
            float b = b1[rr], s = s1[rr];
            int bi = b1i[rr], si = s1i[rr];
            #pragma unroll
            for (int mask = 1; mask <= 8; mask <<= 1) {
                float ov  = __shfl_xor(b, mask);  int oi  = __shfl_xor(bi, mask);
                float ov2 = __shfl_xor(s, mask);  int oi2 = __shfl_xor(si, mask);
                if (ov < b || (ov == b && oi < bi)) {
                    float ns = b; int nsi = bi;
                    if (ov2 < ns) { ns = ov2; nsi = oi2; }
                    b = ov; bi = oi; s = ns; si = nsi;
                } else if (ov < s) { s = ov; si = oi; }
            }
            if ((lane & 15) == 0) {
                int r = wm * 64 + i * 16 + ((lane >> 4) << 2) + reg;
                sv2[wn * 128 + r] = make_float4(b, __int_as_float(bi), s, __int_as_float(si));
            }
        }
    }
    __syncthreads();
    if (tid < 128) {
        float4 A = sv2[tid], C = sv2[128 + tid];
        float a1 = A.x, a2 = A.z, c1 = C.x, c2 = C.z;
        int a1i = __float_as_int(A.y), a2i = __float_as_int(A.w);
        int c1i = __float_as_int(C.y), c2i = __float_as_int(C.w);
        float b, s; int bi, si;
        if (c1 < a1 || (c1 == a1 && c1i < a1i)) {
            b = c1; bi = c1i; s = a1; si = a1i;
            if (c2 < s) { s = c2; si = c2i; }
        } else {
            b = a1; bi = a1i; s = a2; si = a2i;
            if (c1 < s) { s = c1; si = c1i; }
        }
        pairs[(size_t)(m0 + tid) * NSLICE + bS] = make_float4(b, __int_as_float(bi), s, __int_as_float(si));
    }
}

// ---------------- k_refine: slice merge + exact fp32 argmin ----------------
__global__ __launch_bounds__(256)
void k_refine(const float4* __restrict__ pairs, const float* __restrict__ xT,
              const float* __restrict__ emb, const float* __restrict__ esq,
              int* __restrict__ idx_i32, float* __restrict__ out_idxf,
              float* __restrict__ counts) {
    int lane = threadIdx.x & 63;
    int wid  = threadIdx.x >> 6;
    int tok  = blockIdx.x * 4 + wid;

    float4 p = (lane < NSLICE) ? pairs[(size_t)tok * NSLICE + lane]
                               : make_float4(3.4e38f, __int_as_float(0x7fffffff),
                                             3.4e38f, __int_as_float(0x7fffffff));
    float v1 = p.x, v2 = p.z;
    int i1 = __float_as_int(p.y), i2 = __float_as_int(p.w);

    float bv = v1; int bi = i1;
    #pragma unroll
    for (int mask = 1; mask <= 32; mask <<= 1) {
        float ov = __shfl_xor(bv, mask); int oi = __shfl_xor(bi, mask);
        if (ov < bv || (ov == bv && oi < bi)) { bv = ov; bi = oi; }
    }
    float thresh = bv + MARGIN;
    float4 xv = *(const float4*)(xT + (size_t)tok * 256 + lane * 4);

    unsigned long long m1 = __ballot(v1 <= thresh);
    unsigned long long m2 = __ballot(v2 <= thresh);
    float bestd = 3.4e38f; int besti = 0x7fffffff;
    while (m1 | m2) {
        int k;
        if (m1) { int l = __ffsll(m1) - 1; m1 &= m1 - 1; k = __shfl(i1, l); }
        else    { int l = __ffsll(m2) - 1; m2 &= m2 - 1; k = __shfl(i2, l); }
        float4 e4 = *(const float4*)(emb + (size_t)k * EMB_DIM + lane * 4);
        float d = xv.x * e4.x + xv.y * e4.y + xv.z * e4.z + xv.w * e4.w;
        #pragma unroll
        for (int mask = 1; mask <= 32; mask <<= 1) d += __shfl_xor(d, mask);
        float dist = esq[k] - 2.0f * d;
        if (dist < bestd || (dist == bestd && k < besti)) { bestd = dist; besti = k; }
    }
    if (lane == 0) {
        idx_i32[tok] = besti;
        out_idxf[tok] = (float)besti;
        atomicAdd(&counts[besti], 1.0f);
    }
}

// ---------------- k_qst: NCHW-coalesced straight-through + loss ----------------
// Block = 64 consecutive tokens (one batch, hw-run of 64) x all 256 d.
// Phase 1: gather 64 emb rows into padded LDS. Phase 2: coalesced NCHW write.
__global__ __launch_bounds__(256)
void k_qst(const float* __restrict__ x, const float* __restrict__ emb,
           const int* __restrict__ idx_i32, float* __restrict__ out_qst,
           float* __restrict__ loss_parts) {
    __shared__ float Q[64 * 257];   // ~64.25 KB, stride 257 breaks bank conflicts
    int tid = threadIdx.x;
    int lane = tid & 63, w = tid >> 6;
    int tok0 = blockIdx.x * 64;
    int b = tok0 >> 10, hw0 = tok0 & 1023;

    #pragma unroll 4
    for (int s = 0; s < 16; s++) {
        int t = w * 16 + s;
        int k = idx_i32[tok0 + t];
        float4 e4 = *(const float4*)(emb + (size_t)k * EMB_DIM + lane * 4);
        float* q = Q + t * 257 + lane * 4;
        q[0] = e4.x; q[1] = e4.y; q[2] = e4.z; q[3] = e4.w;
    }
    __syncthreads();

    int lane16 = tid & 15, dg = tid >> 4;    // hw = lane16*4.., d = it*16+dg
    int hwoff = lane16 * 4;
    float sq = 0.0f;
    #pragma unroll 4
    for (int it = 0; it < 16; it++) {
        int d = it * 16 + dg;
        const float* xb = x + (size_t)b * 262144 + (size_t)d * 1024 + hw0 + hwoff;
        float4 xv = *(const float4*)xb;
        float q0 = Q[(hwoff + 0) * 257 + d];
        float q1 = Q[(hwoff + 1) * 257 + d];
        float q2 = Q[(hwoff + 2) * 257 + d];
        float q3 = Q[(hwoff + 3) * 257 + d];
        float d0 = q0 - xv.x, d1 = q1 - xv.y, d2 = q2 - xv.z, d3 = q3 - xv.w;
        float4 o; o.x = xv.x + d0; o.y = xv.y + d1; o.z = xv.z + d2; o.w = xv.w + d3;
        *(float4*)(out_qst + (size_t)b * 262144 + (size_t)d * 1024 + hw0 + hwoff) = o;
        sq += d0 * d0 + d1 * d1 + d2 * d2 + d3 * d3;
    }
    #pragma unroll
    for (int m = 32; m >= 1; m >>= 1) sq += __shfl_xor(sq, m);
    __shared__ float wsum[4];
    if ((tid & 63) == 0) wsum[w] = sq;
    __syncthreads();
    if (tid == 0) loss_parts[blockIdx.x] = wsum[0] + wsum[1] + wsum[2] + wsum[3];
}

// ---------------- k_ivt_stats: prefix sum + scatter + n/perplexity/loss -------------
__global__ __launch_bounds__(256)
void k_ivt_stats(const float* __restrict__ counts, const int* __restrict__ idx_i32,
                 const float* __restrict__ cs, const float* __restrict__ loss_parts,
                 int* __restrict__ offsets, int* __restrict__ toklist,
                 float* __restrict__ n_out, float* __restrict__ out) {
    __shared__ int part[256];
    __shared__ int cur[NUM_EMB];
    int t = threadIdx.x;
    int base = t * 32;
    int loc[32]; int s = 0;
    #pragma unroll
    for (int u = 0; u < 32; u++) { loc[u] = s; s += (int)counts[base + u]; }
    part[t] = s;
    __syncthreads();
    for (int off = 1; off < 256; off <<= 1) {
        int add = (t >= off) ? part[t - off] : 0;
        __syncthreads();
        part[t] += add;
        __syncthreads();
    }
    int excl = part[t] - s;
    #pragma unroll
    for (int u = 0; u < 32; u++) {
        int o = excl + loc[u];
        offsets[base + u] = o;
        cur[base + u] = o;
    }
    __syncthreads();
    for (int n = t; n < NTOK; n += 256) {
        int k = idx_i32[n];
        int p = atomicAdd(&cur[k], 1);
        toklist[p] = n;
    }

    float s1 = 0.0f, s2 = 0.0f;
    for (int k = t; k < NUM_EMB; k += 256) {
        float c = counts[k];
        s1 += cs[k] * DECAY + OMD * c;
        float pb = c / (float)NTOK;
        s2 += pb * logf(pb + 1e-10f);
    }
    float s3 = loss_parts[t];
    #pragma unroll
    for (int m = 32; m >= 1; m >>= 1) {
        s1 += __shfl_xor(s1, m);
        s2 += __shfl_xor(s2, m);
        s3 += __shfl_xor(s3, m);
    }
    __shared__ float w1[4], w2[4], w3[4];
    int lane = t & 63, wid = t >> 6;
    if (lane == 0) { w1[wid] = s1; w2[wid] = s2; w3[wid] = s3; }
    __syncthreads();
    if (t == 0) {
        float n  = w1[0] + w1[1] + w1[2] + w1[3];
        float e2 = w2[0] + w2[1] + w2[2] + w2[3];
        float ls = w3[0] + w3[1] + w3[2] + w3[3];
        n_out[0] = n;
        out[4194305] = expf(-e2);                 // perplexity
        out[0] = COMMIT * ls / (float)QELEMS;     // loss
    }
}

// ---------------- k_dw_final: per-code dw row-sum fused with EMA outputs ------------
__global__ __launch_bounds__(64)
void k_dw_final(const float* __restrict__ xT, const float* __restrict__ counts,
                const int* __restrict__ offsets, const int* __restrict__ toklist,
                const float* __restrict__ cs, const float* __restrict__ emaw,
                const float* __restrict__ n_in,
                float* __restrict__ out_emb, float* __restrict__ out_cs,
                float* __restrict__ out_emaw) {
    int k = blockIdx.x;
    int lane = threadIdx.x;
    int c = (int)counts[k];
    int off = offsets[k];
    float a0 = 0, a1 = 0, a2 = 0, a3 = 0;
    for (int t = 0; t < c; t++) {
        int tok = toklist[off + t];
        float4 v = *(const float4*)(xT + (size_t)tok * 256 + lane * 4);
        a0 += v.x; a1 += v.y; a2 += v.z; a3 += v.w;
    }
    float n = n_in[0];
    float pre  = cs[k] * DECAY + OMD * counts[k];
    float cssm = (pre + EPS_) / (n + (float)NUM_EMB * EPS_) * n;
    size_t o = (size_t)k * EMB_DIM + lane * 4;
    float4 ew = *(const float4*)(emaw + o);
    float4 wv;
    wv.x = ew.x * DECAY + OMD * a0;
    wv.y = ew.y * DECAY + OMD * a1;
    wv.z = ew.z * DECAY + OMD * a2;
    wv.w = ew.w * DECAY + OMD * a3;
    *(float4*)(out_emaw + o) = wv;
    float4 obv; obv.x = wv.x / cssm; obv.y = wv.y / cssm; obv.z = wv.z / cssm; obv.w = wv.w / cssm;
    *(float4*)(out_emb + o) = obv;
    if (lane == 0) out_cs[k] = cssm;
}

extern "C" void kernel_launch(void* const* d_in, const int* in_sizes, int n_in,
                              void* d_out, int out_size, void* d_ws, size_t ws_size,
                              hipStream_t stream) {
    const float* x    = (const float*)d_in[0];   // [16,256,32,32]
    const float* emb  = (const float*)d_in[1];   // [8192,256]
    const float* cs   = (const float*)d_in[2];   // [8192]
    const float* emaw = (const float*)d_in[3];   // [8192,256]
    float* out = (float*)d_out;

    // workspace layout (bytes)
    char* W = (char*)d_ws;
    _Float16* Ap      = (_Float16*)(W);             //  8,388,608
    _Float16* Bp      = (_Float16*)(W + 8388608);   //  4,194,304
    float*  xT        = (float*) (W + 12582912);    // 16,777,216
    float4* pairs     = (float4*)(W + 29360128);    //  4,194,304
    float* esq        = (float*) (W + 33554432);    //     32,768
    float* counts     = (float*) (W + 33587200);    //     32,768
    float* loss_parts = (float*) (W + 33619968);    //      1,024
    float* n_scal     = (float*) (W + 33621248);    //          4
    int*   offsets    = (int*)   (W + 33621252);    //     32,768
    int*   toklist    = (int*)   (W + 33654020);    //     65,536
    int*   idx_i32    = (int*)   (W + 33719556);    //     65,536

    hipMemsetAsync(counts, 0, 32768, stream);

    k_prep     <<<5120, 256, 0, stream>>>(x, emb, Ap, Bp, xT, esq);
    k_dist     <<<2048, 256, 0, stream>>>(Ap, Bp, esq, pairs);
    k_refine   <<<4096, 256, 0, stream>>>(pairs, xT, emb, esq, idx_i32,
                                          out + 8396802, counts);
    k_qst      <<<256, 256, 0, stream>>>(x, emb, idx_i32, out + 1, loss_parts);
    k_ivt_stats<<<1, 256, 0, stream>>>(counts, idx_i32, cs, loss_parts,
                                       offsets, toklist, n_scal, out);
    k_dw_final <<<NUM_EMB, 64, 0, stream>>>(xT, counts, offsets, toklist, cs, emaw,
                                            n_scal, out + 4194306, out + 6291458,
                                            out + 6299650);
}

// Round 6
// 362.059 us; speedup vs baseline: 3.4373x; 1.1206x over previous
//
#include <hip/hip_runtime.h>
#include <hip/hip_bf16.h>
#include <math.h>

#define NUM_EMB 8192
#define EMB_DIM 256
#define NTOK    16384      // 16 * 32 * 32
#define HW      1024
#define QELEMS  4194304    // 16 * 256 * 1024
#define DECAY   0.99f
#define OMD     0.01f
#define COMMIT  0.25f
#define EPS_    1e-5f
#define MARGIN  0.6f
#define NSLICE  16         // codes per slice = 512

typedef _Float16 h8 __attribute__((ext_vector_type(8)));
typedef float    f4 __attribute__((ext_vector_type(4)));

#define GLD16(gptr, lptr) \
  __builtin_amdgcn_global_load_lds((const __attribute__((address_space(1))) void*)(gptr), \
                                   (__attribute__((address_space(3))) void*)(lptr), 16, 0, 0)

// ---------------- k_prep: x->Ap(f16)+xT(f32), emb->Bp(f16), esq ----------------
// Ap fragment layout: [(mt*8+kc)*64+lane]*8 halves; token = mt*16+(lane&15),
// d = kc*32 + (lane>>4)*8 + j.   Bp analogous with code rows.
__global__ __launch_bounds__(256)
void k_prep(const float* __restrict__ x, const float* __restrict__ emb,
            _Float16* __restrict__ Ap, _Float16* __restrict__ Bp,
            float* __restrict__ xT, float* __restrict__ esq) {
    int bb = blockIdx.x;
    if (bb < 2048) {
        int g = bb * 256 + threadIdx.x;
        int lane = g & 63;
        int kc = (g >> 6) & 7;
        int mt = g >> 9;                         // 0..1023
        int tok = mt * 16 + (lane & 15);
        int b = tok >> 10, hw = tok & 1023;
        int d0 = kc * 32 + (lane >> 4) * 8;
        const float* src = x + (size_t)b * 262144 + (size_t)d0 * 1024 + hw;
        h8 hi; float tmp[8];
        #pragma unroll
        for (int u = 0; u < 8; u++) {
            float v = src[(size_t)u * 1024];
            hi[u] = (_Float16)v;
            tmp[u] = v;
        }
        *(h8*)(Ap + ((size_t)(mt * 8 + kc) * 64 + lane) * 8) = hi;
        *(float4*)(xT + (size_t)tok * 256 + d0)     = *(float4*)(&tmp[0]);
        *(float4*)(xT + (size_t)tok * 256 + d0 + 4) = *(float4*)(&tmp[4]);
    } else if (bb < 3072) {
        int g = (bb - 2048) * 256 + threadIdx.x;
        int lane = g & 63;
        int kc = (g >> 6) & 7;
        int nt = g >> 9;                         // 0..511
        int n = nt * 16 + (lane & 15);
        int d0 = kc * 32 + (lane >> 4) * 8;
        const float* src = emb + (size_t)n * EMB_DIM + d0;
        h8 hi;
        #pragma unroll
        for (int u = 0; u < 8; u++) hi[u] = (_Float16)src[u];
        *(h8*)(Bp + ((size_t)(nt * 8 + kc) * 64 + lane) * 8) = hi;
    } else {
        int k = (bb - 3072) * 4 + (threadIdx.x >> 6);
        int lane = threadIdx.x & 63;
        const float* row = emb + (size_t)k * EMB_DIM;
        float4 v = *(const float4*)(row + lane * 4);
        float s = v.x * v.x + v.y * v.y + v.z * v.z + v.w * v.w;
        #pragma unroll
        for (int m = 32; m >= 1; m >>= 1) s += __shfl_xor(s, m);
        if (lane == 0) esq[k] = s;
    }
}

// ---------------- k_dist: 64x512 block, 4 waves 2x2, A LDS 32KB, B global->VGPR -----
// Register diet: acc 2x4 (32 AGPR) + top2 32 VGPR -> target 4 waves/SIMD.
__global__ __launch_bounds__(256, 4)
void k_dist(const _Float16* __restrict__ Ap, const _Float16* __restrict__ Bp,
            const float* __restrict__ esq, float4* __restrict__ pairs) {
    __shared__ _Float16 Abuf[4 * 8 * 64 * 8];   // 32 KB
    __shared__ float4 sv2[128];                 // 2 KB merge buffer

    const int tid  = threadIdx.x;
    const int lane = tid & 63;
    const int w    = tid >> 6;
    const int wm   = w >> 1, wn = w & 1;
    const int bS   = blockIdx.x >> 8;           // 0..15 (slice-major: L2 reuse of Bp)
    const int bM   = blockIdx.x & 255;          // 0..255
    const int m0   = bM * 64;

    // stage A tile once: 32 KB contiguous from Ap
    #pragma unroll
    for (int s = 0; s < 8; s++) {
        int idx = s * 256 + tid;                // 16B units
        GLD16(Ap + (size_t)bM * 16384 + (size_t)idx * 8, Abuf + idx * 8);
    }

    float b1[8], s1[8];
    int   b1i[8], s1i[8];
    #pragma unroll
    for (int r = 0; r < 8; r++) {
        b1[r] = 3.4e38f; s1[r] = 3.4e38f;
        b1i[r] = 0x7fffffff; s1i[r] = 0x7fffffff;
    }

    __syncthreads();   // only staging barrier

    #pragma unroll 1
    for (int nt = 0; nt < 4; ++nt) {
        const int n0 = bS * 512 + nt * 128;
        float ev[4];
        #pragma unroll
        for (int j = 0; j < 4; j++) ev[j] = esq[n0 + wn * 64 + j * 16 + (lane & 15)];

        f4 acc[2][4] = {};
        #pragma unroll 2
        for (int kc = 0; kc < 8; ++kc) {
            h8 aF[2], bF[4];
            #pragma unroll
            for (int j = 0; j < 4; j++)
                bF[j] = *(const h8*)(Bp + ((size_t)((bS * 32 + nt * 8 + wn * 4 + j) * 8 + kc) * 64 + lane) * 8);
            #pragma unroll
            for (int i = 0; i < 2; i++)
                aF[i] = *(const h8*)(Abuf + (((wm * 2 + i) * 8 + kc) * 64 + lane) * 8);
            #pragma unroll
            for (int i = 0; i < 2; i++)
                #pragma unroll
                for (int j = 0; j < 4; j++)
                    acc[i][j] = __builtin_amdgcn_mfma_f32_16x16x32_f16(aF[i], bF[j], acc[i][j], 0, 0, 0);
        }
        // running per-lane top-2 update (processed in ascending ki per lane)
        #pragma unroll
        for (int i = 0; i < 2; i++) {
            #pragma unroll
            for (int reg = 0; reg < 4; reg++) {
                const int r = i * 4 + reg;
                #pragma unroll
                for (int j = 0; j < 4; j++) {
                    float dv = fmaf(-2.0f, acc[i][j][reg], ev[j]);
                    int ki = n0 + wn * 64 + j * 16 + (lane & 15);
                    if (dv < b1[r]) { s1[r] = b1[r]; s1i[r] = b1i[r]; b1[r] = dv; b1i[r] = ki; }
                    else if (dv < s1[r]) { s1[r] = dv; s1i[r] = ki; }
                }
            }
        }
    }

    // cross-lane exact top-2 merge, once per block
    #pragma unroll
    for (int i = 0; i < 2; i++) {
        #pragma unroll
        for (int reg = 0; reg < 4; reg++) {
            const int rr = i * 4 + reg;
            float b = b1[rr], s = s1[rr];
            int bi = b1i[rr], si = s1i[rr];
            #pragma unroll
            for (int mask = 1; mask <= 8; mask <<= 1) {
                float ov  = __shfl_xor(b, mask);  int oi  = __shfl_xor(bi, mask);
                float ov2 = __shfl_xor(s, mask);  int oi2 = __shfl_xor(si, mask);
                if (ov < b || (ov == b && oi < bi)) {
                    float ns = b; int nsi = bi;
                    if (ov2 < ns) { ns = ov2; nsi = oi2; }
                    b = ov; bi = oi; s = ns; si = nsi;
                } else if (ov < s) { s = ov; si = oi; }
            }
            if ((lane & 15) == 0) {
                int r = (wm * 2 + i) * 16 + ((lane >> 4) << 2) + reg;
                sv2[wn * 64 + r] = make_float4(b, __int_as_float(bi), s, __int_as_float(si));
            }
        }
    }
    __syncthreads();
    if (tid < 64) {
        float4 A = sv2[tid], C = sv2[64 + tid];
        float a1 = A.x, a2 = A.z, c1 = C.x, c2 = C.z;
        int a1i = __float_as_int(A.y), a2i = __float_as_int(A.w);
        int c1i = __float_as_int(C.y), c2i = __float_as_int(C.w);
        float b, s; int bi, si;
        if (c1 < a1 || (c1 == a1 && c1i < a1i)) {
            b = c1; bi = c1i; s = a1; si = a1i;
            if (c2 < s) { s = c2; si = c2i; }
        } else {
            b = a1; bi = a1i; s = a2; si = a2i;
            if (c1 < s) { s = c1; si = c1i; }
        }
        pairs[(size_t)(m0 + tid) * NSLICE + bS] = make_float4(b, __int_as_float(bi), s, __int_as_float(si));
    }
}

// ---------------- k_refine: slice merge + exact fp32 argmin ----------------
__global__ __launch_bounds__(256)
void k_refine(const float4* __restrict__ pairs, const float* __restrict__ xT,
              const float* __restrict__ emb, const float* __restrict__ esq,
              int* __restrict__ idx_i32, float* __restrict__ out_idxf,
              float* __restrict__ counts) {
    int lane = threadIdx.x & 63;
    int wid  = threadIdx.x >> 6;
    int tok  = blockIdx.x * 4 + wid;

    float4 p = (lane < NSLICE) ? pairs[(size_t)tok * NSLICE + lane]
                               : make_float4(3.4e38f, __int_as_float(0x7fffffff),
                                             3.4e38f, __int_as_float(0x7fffffff));
    float v1 = p.x, v2 = p.z;
    int i1 = __float_as_int(p.y), i2 = __float_as_int(p.w);

    float bv = v1; int bi = i1;
    #pragma unroll
    for (int mask = 1; mask <= 32; mask <<= 1) {
        float ov = __shfl_xor(bv, mask); int oi = __shfl_xor(bi, mask);
        if (ov < bv || (ov == bv && oi < bi)) { bv = ov; bi = oi; }
    }
    float thresh = bv + MARGIN;
    float4 xv = *(const float4*)(xT + (size_t)tok * 256 + lane * 4);

    unsigned long long m1 = __ballot(v1 <= thresh);
    unsigned long long m2 = __ballot(v2 <= thresh);
    float bestd = 3.4e38f; int besti = 0x7fffffff;
    while (m1 | m2) {
        int k;
        if (m1) { int l = __ffsll(m1) - 1; m1 &= m1 - 1; k = __shfl(i1, l); }
        else    { int l = __ffsll(m2) - 1; m2 &= m2 - 1; k = __shfl(i2, l); }
        float4 e4 = *(const float4*)(emb + (size_t)k * EMB_DIM + lane * 4);
        float d = xv.x * e4.x + xv.y * e4.y + xv.z * e4.z + xv.w * e4.w;
        #pragma unroll
        for (int mask = 1; mask <= 32; mask <<= 1) d += __shfl_xor(d, mask);
        float dist = esq[k] - 2.0f * d;
        if (dist < bestd || (dist == bestd && k < besti)) { bestd = dist; besti = k; }
    }
    if (lane == 0) {
        idx_i32[tok] = besti;
        out_idxf[tok] = (float)besti;
        atomicAdd(&counts[besti], 1.0f);
    }
}

// ---------------- k_qst: NCHW-coalesced straight-through + loss ----------------
__global__ __launch_bounds__(256)
void k_qst(const float* __restrict__ x, const float* __restrict__ emb,
           const int* __restrict__ idx_i32, float* __restrict__ out_qst,
           float* __restrict__ loss_parts) {
    __shared__ float Q[64 * 257];   // ~64.25 KB, stride 257 breaks bank conflicts
    int tid = threadIdx.x;
    int lane = tid & 63, w = tid >> 6;
    int tok0 = blockIdx.x * 64;
    int b = tok0 >> 10, hw0 = tok0 & 1023;

    #pragma unroll 4
    for (int s = 0; s < 16; s++) {
        int t = w * 16 + s;
        int k = idx_i32[tok0 + t];
        float4 e4 = *(const float4*)(emb + (size_t)k * EMB_DIM + lane * 4);
        float* q = Q + t * 257 + lane * 4;
        q[0] = e4.x; q[1] = e4.y; q[2] = e4.z; q[3] = e4.w;
    }
    __syncthreads();

    int lane16 = tid & 15, dg = tid >> 4;    // hw = lane16*4.., d = it*16+dg
    int hwoff = lane16 * 4;
    float sq = 0.0f;
    #pragma unroll 4
    for (int it = 0; it < 16; it++) {
        int d = it * 16 + dg;
        const float* xb = x + (size_t)b * 262144 + (size_t)d * 1024 + hw0 + hwoff;
        float4 xv = *(const float4*)xb;
        float q0 = Q[(hwoff + 0) * 257 + d];
        float q1 = Q[(hwoff + 1) * 257 + d];
        float q2 = Q[(hwoff + 2) * 257 + d];
        float q3 = Q[(hwoff + 3) * 257 + d];
        float d0 = q0 - xv.x, d1 = q1 - xv.y, d2 = q2 - xv.z, d3 = q3 - xv.w;
        float4 o; o.x = xv.x + d0; o.y = xv.y + d1; o.z = xv.z + d2; o.w = xv.w + d3;
        *(float4*)(out_qst + (size_t)b * 262144 + (size_t)d * 1024 + hw0 + hwoff) = o;
        sq += d0 * d0 + d1 * d1 + d2 * d2 + d3 * d3;
    }
    #pragma unroll
    for (int m = 32; m >= 1; m >>= 1) sq += __shfl_xor(sq, m);
    __shared__ float wsum[4];
    if ((tid & 63) == 0) wsum[w] = sq;
    __syncthreads();
    if (tid == 0) loss_parts[blockIdx.x] = wsum[0] + wsum[1] + wsum[2] + wsum[3];
}

// ---------------- k_ivt_stats: prefix sum + scatter + n/perplexity/loss -------------
__global__ __launch_bounds__(256)
void k_ivt_stats(const float* __restrict__ counts, const int* __restrict__ idx_i32,
                 const float* __restrict__ cs, const float* __restrict__ loss_parts,
                 int* __restrict__ offsets, int* __restrict__ toklist,
                 float* __restrict__ n_out, float* __restrict__ out) {
    __shared__ int part[256];
    __shared__ int cur[NUM_EMB];
    int t = threadIdx.x;
    int base = t * 32;
    int loc[32]; int s = 0;
    #pragma unroll
    for (int u = 0; u < 32; u++) { loc[u] = s; s += (int)counts[base + u]; }
    part[t] = s;
    __syncthreads();
    for (int off = 1; off < 256; off <<= 1) {
        int add = (t >= off) ? part[t - off] : 0;
        __syncthreads();
        part[t] += add;
        __syncthreads();
    }
    int excl = part[t] - s;
    #pragma unroll
    for (int u = 0; u < 32; u++) {
        int o = excl + loc[u];
        offsets[base + u] = o;
        cur[base + u] = o;
    }
    __syncthreads();
    for (int n = t; n < NTOK; n += 256) {
        int k = idx_i32[n];
        int p = atomicAdd(&cur[k], 1);
        toklist[p] = n;
    }

    float s1 = 0.0f, s2 = 0.0f;
    for (int k = t; k < NUM_EMB; k += 256) {
        float c = counts[k];
        s1 += cs[k] * DECAY + OMD * c;
        float pb = c / (float)NTOK;
        s2 += pb * logf(pb + 1e-10f);
    }
    float s3 = loss_parts[t];
    #pragma unroll
    for (int m = 32; m >= 1; m >>= 1) {
        s1 += __shfl_xor(s1, m);
        s2 += __shfl_xor(s2, m);
        s3 += __shfl_xor(s3, m);
    }
    __shared__ float w1[4], w2[4], w3[4];
    int lane = t & 63, wid = t >> 6;
    if (lane == 0) { w1[wid] = s1; w2[wid] = s2; w3[wid] = s3; }
    __syncthreads();
    if (t == 0) {
        float n  = w1[0] + w1[1] + w1[2] + w1[3];
        float e2 = w2[0] + w2[1] + w2[2] + w2[3];
        float ls = w3[0] + w3[1] + w3[2] + w3[3];
        n_out[0] = n;
        out[4194305] = expf(-e2);                 // perplexity
        out[0] = COMMIT * ls / (float)QELEMS;     // loss
    }
}

// ---------------- k_dw_final: per-code dw row-sum fused with EMA outputs ------------
__global__ __launch_bounds__(64)
void k_dw_final(const float* __restrict__ xT, const float* __restrict__ counts,
                const int* __restrict__ offsets, const int* __restrict__ toklist,
                const float* __restrict__ cs, const float* __restrict__ emaw,
                const float* __restrict__ n_in,
                float* __restrict__ out_emb, float* __restrict__ out_cs,
                float* __restrict__ out_emaw) {
    int k = blockIdx.x;
    int lane = threadIdx.x;
    int c = (int)counts[k];
    int off = offsets[k];
    float a0 = 0, a1 = 0, a2 = 0, a3 = 0;
    for (int t = 0; t < c; t++) {
        int tok = toklist[off + t];
        float4 v = *(const float4*)(xT + (size_t)tok * 256 + lane * 4);
        a0 += v.x; a1 += v.y; a2 += v.z; a3 += v.w;
    }
    float n = n_in[0];
    float pre  = cs[k] * DECAY + OMD * counts[k];
    float cssm = (pre + EPS_) / (n + (float)NUM_EMB * EPS_) * n;
    size_t o = (size_t)k * EMB_DIM + lane * 4;
    float4 ew = *(const float4*)(emaw + o);
    float4 wv;
    wv.x = ew.x * DECAY + OMD * a0;
    wv.y = ew.y * DECAY + OMD * a1;
    wv.z = ew.z * DECAY + OMD * a2;
    wv.w = ew.w * DECAY + OMD * a3;
    *(float4*)(out_emaw + o) = wv;
    float4 obv; obv.x = wv.x / cssm; obv.y = wv.y / cssm; obv.z = wv.z / cssm; obv.w = wv.w / cssm;
    *(float4*)(out_emb + o) = obv;
    if (lane == 0) out_cs[k] = cssm;
}

extern "C" void kernel_launch(void* const* d_in, const int* in_sizes, int n_in,
                              void* d_out, int out_size, void* d_ws, size_t ws_size,
                              hipStream_t stream) {
    const float* x    = (const float*)d_in[0];   // [16,256,32,32]
    const float* emb  = (const float*)d_in[1];   // [8192,256]
    const float* cs   = (const float*)d_in[2];   // [8192]
    const float* emaw = (const float*)d_in[3];   // [8192,256]
    float* out = (float*)d_out;

    // workspace layout (bytes)
    char* W = (char*)d_ws;
    _Float16* Ap      = (_Float16*)(W);             //  8,388,608
    _Float16* Bp      = (_Float16*)(W + 8388608);   //  4,194,304
    float*  xT        = (float*) (W + 12582912);    // 16,777,216
    float4* pairs     = (float4*)(W + 29360128);    //  4,194,304
    float* esq        = (float*) (W + 33554432);    //     32,768
    float* counts     = (float*) (W + 33587200);    //     32,768
    float* loss_parts = (float*) (W + 33619968);    //      1,024
    float* n_scal     = (float*) (W + 33621248);    //          4
    int*   offsets    = (int*)   (W + 33621252);    //     32,768
    int*   toklist    = (int*)   (W + 33654020);    //     65,536
    int*   idx_i32    = (int*)   (W + 33719556);    //     65,536

    hipMemsetAsync(counts, 0, 32768, stream);

    k_prep     <<<5120, 256, 0, stream>>>(x, emb, Ap, Bp, xT, esq);
    k_dist     <<<4096, 256, 0, stream>>>(Ap, Bp, esq, pairs);
    k_refine   <<<4096, 256, 0, stream>>>(pairs, xT, emb, esq, idx_i32,
                                          out + 8396802, counts);
    k_qst      <<<256, 256, 0, stream>>>(x, emb, idx_i32, out + 1, loss_parts);
    k_ivt_stats<<<1, 256, 0, stream>>>(counts, idx_i32, cs, loss_parts,
                                       offsets, toklist, n_scal, out);
    k_dw_final <<<NUM_EMB, 64, 0, stream>>>(xT, counts, offsets, toklist, cs, emaw,
                                            n_scal, out + 4194306, out + 6291458,
                                            out + 6299650);
}

// Round 7
// 315.831 us; speedup vs baseline: 3.9404x; 1.1464x over previous
//
#include <hip/hip_runtime.h>
#include <hip/hip_bf16.h>
#include <math.h>

#define NUM_EMB 8192
#define EMB_DIM 256
#define NTOK    16384      // 16 * 32 * 32
#define HW      1024
#define QELEMS  4194304    // 16 * 256 * 1024
#define DECAY   0.99f
#define OMD     0.01f
#define COMMIT  0.25f
#define EPS_    1e-5f
#define MARGIN  0.6f
#define NSLICE  16         // codes per slice = 512

typedef _Float16 h8 __attribute__((ext_vector_type(8)));
typedef float    f4 __attribute__((ext_vector_type(4)));

#define GLD16(gptr, lptr) \
  __builtin_amdgcn_global_load_lds((const __attribute__((address_space(1))) void*)(gptr), \
                                   (__attribute__((address_space(3))) void*)(lptr), 16, 0, 0)

// ---------------- k_prep: x->Ap(f16)+xT(f32), emb->Bp(f16), esq, zero counts --------
__global__ __launch_bounds__(256)
void k_prep(const float* __restrict__ x, const float* __restrict__ emb,
            _Float16* __restrict__ Ap, _Float16* __restrict__ Bp,
            float* __restrict__ xT, float* __restrict__ esq,
            float* __restrict__ counts) {
    int bb = blockIdx.x;
    if (bb < 2048) {
        int g = bb * 256 + threadIdx.x;
        int lane = g & 63;
        int kc = (g >> 6) & 7;
        int mt = g >> 9;                         // 0..1023
        int tok = mt * 16 + (lane & 15);
        int b = tok >> 10, hw = tok & 1023;
        int d0 = kc * 32 + (lane >> 4) * 8;
        const float* src = x + (size_t)b * 262144 + (size_t)d0 * 1024 + hw;
        h8 hi; float tmp[8];
        #pragma unroll
        for (int u = 0; u < 8; u++) {
            float v = src[(size_t)u * 1024];
            hi[u] = (_Float16)v;
            tmp[u] = v;
        }
        *(h8*)(Ap + ((size_t)(mt * 8 + kc) * 64 + lane) * 8) = hi;
        *(float4*)(xT + (size_t)tok * 256 + d0)     = *(float4*)(&tmp[0]);
        *(float4*)(xT + (size_t)tok * 256 + d0 + 4) = *(float4*)(&tmp[4]);
    } else if (bb < 3072) {
        int g = (bb - 2048) * 256 + threadIdx.x;
        int lane = g & 63;
        int kc = (g >> 6) & 7;
        int nt = g >> 9;                         // 0..511
        int n = nt * 16 + (lane & 15);
        int d0 = kc * 32 + (lane >> 4) * 8;
        const float* src = emb + (size_t)n * EMB_DIM + d0;
        h8 hi;
        #pragma unroll
        for (int u = 0; u < 8; u++) hi[u] = (_Float16)src[u];
        *(h8*)(Bp + ((size_t)(nt * 8 + kc) * 64 + lane) * 8) = hi;
    } else if (bb < 5120) {
        int k = (bb - 3072) * 4 + (threadIdx.x >> 6);
        int lane = threadIdx.x & 63;
        const float* row = emb + (size_t)k * EMB_DIM;
        float4 v = *(const float4*)(row + lane * 4);
        float s = v.x * v.x + v.y * v.y + v.z * v.z + v.w * v.w;
        #pragma unroll
        for (int m = 32; m >= 1; m >>= 1) s += __shfl_xor(s, m);
        if (lane == 0) esq[k] = s;
    } else {
        counts[(bb - 5120) * 256 + threadIdx.x] = 0.0f;
    }
}

// ---------------- k_dist: 64x512 block, pipelined B global->VGPR, packed top-2 ------
// Biased distance dv = (esq+4096) - 2*dot in (4096,8192) -> fixed exponent; low 4
// mantissa bits carry (nt<<2)|j. Integer min/max keeps top-2 per lane, 3 ops/elem.
__global__ __launch_bounds__(256, 4)
void k_dist(const _Float16* __restrict__ Ap, const _Float16* __restrict__ Bp,
            const float* __restrict__ esq, float4* __restrict__ pairs) {
    __shared__ _Float16 Abuf[64 * 256];     // 32 KB
    __shared__ float4 sv2[128];             // 2 KB merge buffer

    const int tid    = threadIdx.x;
    const int lane   = tid & 63;
    const int lane16 = lane & 15;
    const int w      = tid >> 6;
    const int wm     = w >> 1, wn = w & 1;
    const int bS     = blockIdx.x >> 8;     // 0..15 (slice-major: L2 reuse of Bp)
    const int bM     = blockIdx.x & 255;    // 0..255
    const int m0     = bM * 64;

    // stage A tile once: 32 KB contiguous from Ap
    #pragma unroll
    for (int s = 0; s < 8; s++) {
        int idx = s * 256 + tid;
        GLD16(Ap + (size_t)bM * 16384 + (size_t)idx * 8, Abuf + idx * 8);
    }

    // preload biased esq for all (nt, j) this lane will see
    float ev[16];
    #pragma unroll
    for (int nt = 0; nt < 4; nt++)
        #pragma unroll
        for (int j = 0; j < 4; j++)
            ev[nt * 4 + j] = esq[bS * 512 + nt * 128 + wn * 64 + j * 16 + lane16] + 4096.0f;

    int b1[8], s1[8];
    #pragma unroll
    for (int r = 0; r < 8; r++) { b1[r] = 0x7f7fffff; s1[r] = 0x7f7fffff; }

    __syncthreads();   // only staging barrier

    const _Float16* Bbase = Bp + (size_t)bS * 131072 + (size_t)wn * 16384 + (size_t)lane * 8;

    f4 acc[2][4] = {};
    h8 bFn[4];
    #pragma unroll
    for (int j = 0; j < 4; j++) bFn[j] = *(const h8*)(Bbase + j * 4096);

    #pragma unroll 2
    for (int t = 0; t < 32; t++) {
        const int nt = t >> 3, kc = t & 7;
        h8 bF[4];
        #pragma unroll
        for (int j = 0; j < 4; j++) bF[j] = bFn[j];
        if (t < 31) {
            const int t1 = t + 1;
            const int nt1 = t1 >> 3, kc1 = t1 & 7;
            #pragma unroll
            for (int j = 0; j < 4; j++)
                bFn[j] = *(const h8*)(Bbase + nt1 * 32768 + j * 4096 + kc1 * 512);
        }
        h8 aF[2];
        #pragma unroll
        for (int i = 0; i < 2; i++)
            aF[i] = *(const h8*)(Abuf + (((wm * 2 + i) * 8 + kc) * 64 + lane) * 8);
        #pragma unroll
        for (int i = 0; i < 2; i++)
            #pragma unroll
            for (int j = 0; j < 4; j++)
                acc[i][j] = __builtin_amdgcn_mfma_f32_16x16x32_f16(aF[i], bF[j], acc[i][j], 0, 0, 0);

        if (kc == 7) {   // per-nt epilogue: packed top-2 update, then reset acc
            #pragma unroll
            for (int i = 0; i < 2; i++)
                #pragma unroll
                for (int reg = 0; reg < 4; reg++) {
                    const int r = i * 4 + reg;
                    #pragma unroll
                    for (int j = 0; j < 4; j++) {
                        float dv = fmaf(-2.0f, acc[i][j][reg], ev[nt * 4 + j]);
                        int iv = (__float_as_int(dv) & ~0xF) | (nt << 2) | j;
                        int mx = max(b1[r], iv);
                        b1[r] = min(b1[r], iv);
                        s1[r] = min(s1[r], mx);
                    }
                }
            #pragma unroll
            for (int i = 0; i < 2; i++)
                #pragma unroll
                for (int j = 0; j < 4; j++)
                    acc[i][j] = (f4){0.0f, 0.0f, 0.0f, 0.0f};
        }
    }

    // unpack (nt,j) codes -> full indices, then cross-lane16 exact top-2 merge
    #pragma unroll
    for (int i = 0; i < 2; i++) {
        #pragma unroll
        for (int reg = 0; reg < 4; reg++) {
            const int rr = i * 4 + reg;
            int bv = b1[rr], sv = s1[rr];
            int bki = bS * 512 + ((bv >> 2) & 3) * 128 + (bv & 3) * 16 + wn * 64 + lane16;
            int ski = bS * 512 + ((sv >> 2) & 3) * 128 + (sv & 3) * 16 + wn * 64 + lane16;
            #pragma unroll
            for (int mask = 1; mask <= 8; mask <<= 1) {
                int ov  = __shfl_xor(bv, mask);  int oki  = __shfl_xor(bki, mask);
                int ov2 = __shfl_xor(sv, mask);  int oki2 = __shfl_xor(ski, mask);
                if (ov < bv || (ov == bv && oki < bki)) {
                    int ns = bv; int nsi = bki;
                    if (ov2 < ns) { ns = ov2; nsi = oki2; }
                    bv = ov; bki = oki; sv = ns; ski = nsi;
                } else if (ov < sv) { sv = ov; ski = oki; }
            }
            if (lane16 == 0) {
                int r = (wm * 2 + i) * 16 + ((lane >> 4) << 2) + reg;
                sv2[wn * 64 + r] = make_float4(__int_as_float(bv), __int_as_float(bki),
                                               __int_as_float(sv), __int_as_float(ski));
            }
        }
    }
    __syncthreads();
    if (tid < 64) {
        float4 A = sv2[tid], C = sv2[64 + tid];
        float a1 = A.x, a2 = A.z, c1 = C.x, c2 = C.z;
        int a1i = __float_as_int(A.y), a2i = __float_as_int(A.w);
        int c1i = __float_as_int(C.y), c2i = __float_as_int(C.w);
        float b, s; int bi, si;
        if (c1 < a1 || (c1 == a1 && c1i < a1i)) {
            b = c1; bi = c1i; s = a1; si = a1i;
            if (c2 < s) { s = c2; si = c2i; }
        } else {
            b = a1; bi = a1i; s = a2; si = a2i;
            if (c1 < s) { s = c1; si = c1i; }
        }
        pairs[(size_t)(m0 + tid) * NSLICE + bS] = make_float4(b, __int_as_float(bi), s, __int_as_float(si));
    }
}

// ---------------- k_rq: fused refine (exact fp32 argmin) + coalesced q_st + loss ----
// Block = 64 consecutive tokens, 512 threads (8 waves x 8 tokens each).
__global__ __launch_bounds__(512)
void k_rq(const float4* __restrict__ pairs, const float* __restrict__ xT,
          const float* __restrict__ emb, const float* __restrict__ esq,
          const float* __restrict__ x,
          int* __restrict__ idx_i32, float* __restrict__ out_idxf,
          float* __restrict__ counts, float* __restrict__ out_qst,
          float* __restrict__ loss_parts) {
    __shared__ float Q[64 * 257];   // winner rows, stride 257
    __shared__ float wsum[8];
    int tid = threadIdx.x;
    int lane = tid & 63, wid = tid >> 6;
    int tok0 = blockIdx.x * 64;
    int b = tok0 >> 10, hw0 = tok0 & 1023;

    for (int s = 0; s < 8; s++) {
        int tl = wid * 8 + s;
        int tok = tok0 + tl;
        float4 p = (lane < NSLICE) ? pairs[(size_t)tok * NSLICE + lane]
                                   : make_float4(3.4e38f, __int_as_float(0x7fffffff),
                                                 3.4e38f, __int_as_float(0x7fffffff));
        float v1 = p.x, v2 = p.z;
        int i1 = __float_as_int(p.y), i2 = __float_as_int(p.w);

        float bv = v1; int bi = i1;
        #pragma unroll
        for (int mask = 1; mask <= 32; mask <<= 1) {
            float ov = __shfl_xor(bv, mask); int oi = __shfl_xor(bi, mask);
            if (ov < bv || (ov == bv && oi < bi)) { bv = ov; bi = oi; }
        }
        float thresh = bv + MARGIN;
        float4 xv = *(const float4*)(xT + (size_t)tok * 256 + lane * 4);

        unsigned long long m1 = __ballot(v1 <= thresh);
        unsigned long long m2 = __ballot(v2 <= thresh);
        float bestd = 3.4e38f; int besti = 0x7fffffff;
        while (m1 | m2) {
            int k;
            if (m1) { int l = __ffsll(m1) - 1; m1 &= m1 - 1; k = __shfl(i1, l); }
            else    { int l = __ffsll(m2) - 1; m2 &= m2 - 1; k = __shfl(i2, l); }
            float4 e4 = *(const float4*)(emb + (size_t)k * EMB_DIM + lane * 4);
            float d = xv.x * e4.x + xv.y * e4.y + xv.z * e4.z + xv.w * e4.w;
            #pragma unroll
            for (int mask = 1; mask <= 32; mask <<= 1) d += __shfl_xor(d, mask);
            float dist = esq[k] - 2.0f * d;
            if (dist < bestd || (dist == bestd && k < besti)) { bestd = dist; besti = k; }
        }
        // stash winner row into LDS
        float4 e4 = *(const float4*)(emb + (size_t)besti * EMB_DIM + lane * 4);
        float* q = Q + tl * 257 + lane * 4;
        q[0] = e4.x; q[1] = e4.y; q[2] = e4.z; q[3] = e4.w;
        if (lane == 0) {
            idx_i32[tok] = besti;
            out_idxf[tok] = (float)besti;
            atomicAdd(&counts[besti], 1.0f);
        }
    }
    __syncthreads();

    // phase 2: coalesced NCHW straight-through write + loss
    int lane16 = tid & 15, dg = tid >> 4;      // dg 0..31
    int hwoff = lane16 * 4;
    float sq = 0.0f;
    #pragma unroll 2
    for (int it = 0; it < 8; it++) {
        int d = it * 32 + dg;
        const float* xb = x + (size_t)b * 262144 + (size_t)d * 1024 + hw0 + hwoff;
        float4 xv = *(const float4*)xb;
        float q0 = Q[(hwoff + 0) * 257 + d];
        float q1 = Q[(hwoff + 1) * 257 + d];
        float q2 = Q[(hwoff + 2) * 257 + d];
        float q3 = Q[(hwoff + 3) * 257 + d];
        float d0 = q0 - xv.x, d1 = q1 - xv.y, d2 = q2 - xv.z, d3 = q3 - xv.w;
        float4 o; o.x = xv.x + d0; o.y = xv.y + d1; o.z = xv.z + d2; o.w = xv.w + d3;
        *(float4*)(out_qst + (size_t)b * 262144 + (size_t)d * 1024 + hw0 + hwoff) = o;
        sq += d0 * d0 + d1 * d1 + d2 * d2 + d3 * d3;
    }
    #pragma unroll
    for (int m = 32; m >= 1; m >>= 1) sq += __shfl_xor(sq, m);
    if (lane == 0) wsum[wid] = sq;
    __syncthreads();
    if (tid == 0) {
        float t = 0.0f;
        #pragma unroll
        for (int u = 0; u < 8; u++) t += wsum[u];
        loss_parts[blockIdx.x] = t;
    }
}

// ---------------- k_ivt_stats: prefix sum + scatter + n/perplexity/loss -------------
__global__ __launch_bounds__(256)
void k_ivt_stats(const float* __restrict__ counts, const int* __restrict__ idx_i32,
                 const float* __restrict__ cs, const float* __restrict__ loss_parts,
                 int* __restrict__ offsets, int* __restrict__ toklist,
                 float* __restrict__ n_out, float* __restrict__ out) {
    __shared__ int part[256];
    __shared__ int cur[NUM_EMB];
    int t = threadIdx.x;
    int base = t * 32;
    int loc[32]; int s = 0;
    #pragma unroll
    for (int u = 0; u < 32; u++) { loc[u] = s; s += (int)counts[base + u]; }
    part[t] = s;
    __syncthreads();
    for (int off = 1; off < 256; off <<= 1) {
        int add = (t >= off) ? part[t - off] : 0;
        __syncthreads();
        part[t] += add;
        __syncthreads();
    }
    int excl = part[t] - s;
    #pragma unroll
    for (int u = 0; u < 32; u++) {
        int o = excl + loc[u];
        offsets[base + u] = o;
        cur[base + u] = o;
    }
    __syncthreads();
    for (int n = t; n < NTOK; n += 256) {
        int k = idx_i32[n];
        int p = atomicAdd(&cur[k], 1);
        toklist[p] = n;
    }

    float s1 = 0.0f, s2 = 0.0f;
    for (int k = t; k < NUM_EMB; k += 256) {
        float c = counts[k];
        s1 += cs[k] * DECAY + OMD * c;
        float pb = c / (float)NTOK;
        s2 += pb * logf(pb + 1e-10f);
    }
    float s3 = loss_parts[t];
    #pragma unroll
    for (int m = 32; m >= 1; m >>= 1) {
        s1 += __shfl_xor(s1, m);
        s2 += __shfl_xor(s2, m);
        s3 += __shfl_xor(s3, m);
    }
    __shared__ float w1[4], w2[4], w3[4];
    int lane = t & 63, wid = t >> 6;
    if (lane == 0) { w1[wid] = s1; w2[wid] = s2; w3[wid] = s3; }
    __syncthreads();
    if (t == 0) {
        float n  = w1[0] + w1[1] + w1[2] + w1[3];
        float e2 = w2[0] + w2[1] + w2[2] + w2[3];
        float ls = w3[0] + w3[1] + w3[2] + w3[3];
        n_out[0] = n;
        out[4194305] = expf(-e2);                 // perplexity
        out[0] = COMMIT * ls / (float)QELEMS;     // loss
    }
}

// ---------------- k_dw_final: 2-wave per-code dw row-sum + EMA outputs --------------
__global__ __launch_bounds__(128)
void k_dw_final(const float* __restrict__ xT, const float* __restrict__ counts,
                const int* __restrict__ offsets, const int* __restrict__ toklist,
                const float* __restrict__ cs, const float* __restrict__ emaw,
                const float* __restrict__ n_in,
                float* __restrict__ out_emb, float* __restrict__ out_cs,
                float* __restrict__ out_emaw) {
    __shared__ float4 sbuf[2][64];
    int k = blockIdx.x;
    int lane = threadIdx.x & 63, wid = threadIdx.x >> 6;
    int c = (int)counts[k];
    int off = offsets[k];
    float a0 = 0, a1 = 0, a2 = 0, a3 = 0;
    for (int t = wid; t < c; t += 2) {
        int tok = toklist[off + t];
        float4 v = *(const float4*)(xT + (size_t)tok * 256 + lane * 4);
        a0 += v.x; a1 += v.y; a2 += v.z; a3 += v.w;
    }
    sbuf[wid][lane] = make_float4(a0, a1, a2, a3);
    __syncthreads();
    if (wid == 0) {
        float4 p0 = sbuf[0][lane], p1 = sbuf[1][lane];
        a0 = p0.x + p1.x; a1 = p0.y + p1.y; a2 = p0.z + p1.z; a3 = p0.w + p1.w;
        float n = n_in[0];
        float pre  = cs[k] * DECAY + OMD * counts[k];
        float cssm = (pre + EPS_) / (n + (float)NUM_EMB * EPS_) * n;
        size_t o = (size_t)k * EMB_DIM + lane * 4;
        float4 ew = *(const float4*)(emaw + o);
        float4 wv;
        wv.x = ew.x * DECAY + OMD * a0;
        wv.y = ew.y * DECAY + OMD * a1;
        wv.z = ew.z * DECAY + OMD * a2;
        wv.w = ew.w * DECAY + OMD * a3;
        *(float4*)(out_emaw + o) = wv;
        float4 obv; obv.x = wv.x / cssm; obv.y = wv.y / cssm;
        obv.z = wv.z / cssm; obv.w = wv.w / cssm;
        *(float4*)(out_emb + o) = obv;
        if (lane == 0) out_cs[k] = cssm;
    }
}

extern "C" void kernel_launch(void* const* d_in, const int* in_sizes, int n_in,
                              void* d_out, int out_size, void* d_ws, size_t ws_size,
                              hipStream_t stream) {
    const float* x    = (const float*)d_in[0];   // [16,256,32,32]
    const float* emb  = (const float*)d_in[1];   // [8192,256]
    const float* cs   = (const float*)d_in[2];   // [8192]
    const float* emaw = (const float*)d_in[3];   // [8192,256]
    float* out = (float*)d_out;

    // workspace layout (bytes)
    char* W = (char*)d_ws;
    _Float16* Ap      = (_Float16*)(W);             //  8,388,608
    _Float16* Bp      = (_Float16*)(W + 8388608);   //  4,194,304
    float*  xT        = (float*) (W + 12582912);    // 16,777,216
    float4* pairs     = (float4*)(W + 29360128);    //  4,194,304
    float* esq        = (float*) (W + 33554432);    //     32,768
    float* counts     = (float*) (W + 33587200);    //     32,768
    float* loss_parts = (float*) (W + 33619968);    //      1,024
    float* n_scal     = (float*) (W + 33621248);    //          4
    int*   offsets    = (int*)   (W + 33621252);    //     32,768
    int*   toklist    = (int*)   (W + 33654020);    //     65,536
    int*   idx_i32    = (int*)   (W + 33719556);    //     65,536

    k_prep     <<<5152, 256, 0, stream>>>(x, emb, Ap, Bp, xT, esq, counts);
    k_dist     <<<4096, 256, 0, stream>>>(Ap, Bp, esq, pairs);
    k_rq       <<<256, 512, 0, stream>>>(pairs, xT, emb, esq, x, idx_i32,
                                         out + 8396802, counts, out + 1, loss_parts);
    k_ivt_stats<<<1, 256, 0, stream>>>(counts, idx_i32, cs, loss_parts,
                                       offsets, toklist, n_scal, out);
    k_dw_final <<<NUM_EMB, 128, 0, stream>>>(xT, counts, offsets, toklist, cs, emaw,
                                             n_scal, out + 4194306, out + 6291458,
                                             out + 6299650);
}